// Round 16
// baseline (556.860 us; speedup 1.0000x reference)
//
#include <hip/hip_runtime.h>
#include <hip/hip_bf16.h>

#define N_NODES 50000
#define N_EDGES 800000
#define D 128
#define NH 8
#define DH 16
#define DFF 256
#define LN_EPS 1e-5f
#define GN 16
#define NPB 32
#define SCAN_BS 512
#define NSCAN ((N_NODES + SCAN_BS - 1) / SCAN_BS)  // 98

typedef __attribute__((ext_vector_type(8))) short bf16x8;
typedef __attribute__((ext_vector_type(8))) unsigned short u16x8;
typedef __attribute__((ext_vector_type(4))) float f32x4;
typedef unsigned short ushort_t;

__device__ __forceinline__ float wred(float v) {
#pragma unroll
    for (int o = 32; o; o >>= 1) v += __shfl_xor(v, o);
    return v;
}

// fp32 -> bf16 (RNE) bit helper
__device__ __forceinline__ short f2b(float f) {
    unsigned u = __float_as_uint(f);
    unsigned r = u + 0x7fffu + ((u >> 16) & 1u);
    return (short)(r >> 16);
}
__device__ __forceinline__ float b2f(unsigned short u) {
    return __uint_as_float((unsigned)u << 16);
}

// K0: zero the degree array.
__global__ __launch_bounds__(256) void k_zero(int* __restrict__ p) {
    int i = blockIdx.x * 256 + threadIdx.x;
    if (i < N_NODES) p[i] = 0;
}

// K1: q/k projections -> bf16. 16 nodes per 128-thread block.
__global__ __launch_bounds__(128) void k_qkproj(
    const float* __restrict__ x, const float* __restrict__ Wk,
    const float* __restrict__ Wq, ushort_t* __restrict__ kout,
    ushort_t* __restrict__ qout) {
    __shared__ float xs[16][128];
    const int t = threadIdx.x;
    const int nb = blockIdx.x * 16;
#pragma unroll
    for (int r = 0; r < 16; ++r) xs[r][t] = x[(size_t)(nb + r) * D + t];
    __syncthreads();
    const float4* wk4 = (const float4*)(Wk + (size_t)t * D);
    const float4* wq4 = (const float4*)(Wq + (size_t)t * D);
    float ka[16] = {}, qa[16] = {};
#pragma unroll 4
    for (int i4 = 0; i4 < 32; ++i4) {
        float4 wk = wk4[i4], wq = wq4[i4];
#pragma unroll
        for (int r = 0; r < 16; ++r) {
            float4 xv = *(const float4*)&xs[r][i4 * 4];
            ka[r] += wk.x * xv.x + wk.y * xv.y + wk.z * xv.z + wk.w * xv.w;
            qa[r] += wq.x * xv.x + wq.y * xv.y + wq.z * xv.z + wq.w * xv.w;
        }
    }
#pragma unroll
    for (int r = 0; r < 16; ++r) {
        kout[(size_t)(nb + r) * D + t] = (ushort_t)f2b(ka[r]);
        qout[(size_t)(nb + r) * D + t] = (ushort_t)f2b(qa[r]);
    }
}

// CSR build ---------------------------------------------------------------
__global__ __launch_bounds__(256) void k_hist(const int* __restrict__ dst,
                                              int* __restrict__ deg) {
    int e = blockIdx.x * 256 + threadIdx.x;
    atomicAdd(&deg[dst[e]], 1);
}

__global__ __launch_bounds__(SCAN_BS) void k_scan1(
    const int* __restrict__ deg, int* __restrict__ scanout,
    int* __restrict__ bsum) {
    __shared__ int ss[SCAN_BS];
    const int t = threadIdx.x;
    const int i = blockIdx.x * SCAN_BS + t;
    int v = (i < N_NODES) ? deg[i] : 0;
    ss[t] = v;
    __syncthreads();
    for (int off = 1; off < SCAN_BS; off <<= 1) {
        int a = (t >= off) ? ss[t - off] : 0;
        __syncthreads();
        ss[t] += a;
        __syncthreads();
    }
    if (i < N_NODES) scanout[i] = ss[t] - v;
    if (t == SCAN_BS - 1) bsum[blockIdx.x] = ss[t];
}

__global__ __launch_bounds__(128) void k_scan2(int* __restrict__ bsum) {
    __shared__ int ss[128];
    const int t = threadIdx.x;
    int v = (t < NSCAN) ? bsum[t] : 0;
    ss[t] = v;
    __syncthreads();
    for (int off = 1; off < 128; off <<= 1) {
        int a = (t >= off) ? ss[t - off] : 0;
        __syncthreads();
        ss[t] += a;
        __syncthreads();
    }
    if (t < NSCAN) bsum[t] = ss[t] - v;
}

__global__ __launch_bounds__(256) void k_scan3(
    const int* __restrict__ scanout, const int* __restrict__ bsum,
    int* __restrict__ rowstart, int* __restrict__ cursor) {
    int i = blockIdx.x * 256 + threadIdx.x;
    if (i < N_NODES) {
        int rs = scanout[i] + bsum[i / SCAN_BS];
        rowstart[i] = rs;
        cursor[i] = rs;
    }
    if (i == 0) rowstart[N_NODES] = N_EDGES;
}

__global__ __launch_bounds__(256) void k_fill(const int* __restrict__ dst,
                                              int* __restrict__ cursor,
                                              int* __restrict__ eidx) {
    int e = blockIdx.x * 256 + threadIdx.x;
    int pos = atomicAdd(&cursor[dst[e]], 1);
    eidx[pos] = e;
}

// K3: FULLY FUSED attention + weighted-sum + projection.
// Per edge (single pass): p_h = exp(dot(q_h,k_h)/4 + basic*wd_h) computed
// in-wave (3 shfl_xor reduce per 8-lane head group, 1 exp/lane, 8 shfl
// broadcasts); accumulate p_h*bond into sacc[8][2] and p_h into psum[8].
// End of node: ft = MFMA(Wv, sacc/psum). No aperm buffer, no k_attn kernel.
__global__ __launch_bounds__(256) void k_hsum(
    const float* __restrict__ bond, const ushort_t* __restrict__ kbf,
    const ushort_t* __restrict__ qbf, const float* __restrict__ basic,
    const float* __restrict__ Wdis, const int* __restrict__ src,
    const float* __restrict__ Wv, const int* __restrict__ rowstart,
    const int* __restrict__ eidx, float* __restrict__ ft) {
    __shared__ short slds[8 * 16 * 128];  // [head][node][k] bf16, swizzled
    __shared__ int srs[GN + 1];
    const int t = threadIdx.x;
    const int lane = t & 63, w = t >> 6;
    const int lr = lane & 15, lg = lane >> 4;
    const int n0 = blockIdx.x * GN;
    if (t < GN + 1) srs[t] = rowstart[n0 + t];
    __syncthreads();

    const int c0 = lane * 2;
    const int chunk = lane >> 2;
    const int elo = (lane * 2) & 7;
    const float wd = Wdis[lane >> 3];

    // ---- Phase A: each wave owns nodes w, w+4, w+8, w+12 ----
#pragma unroll
    for (int i = 0; i < 4; ++i) {
        int ln = w + i * 4;
        int node = n0 + ln;
        int rs = srs[ln], re = srs[ln + 1];
        unsigned qu = *(const unsigned*)&qbf[(size_t)node * D + c0];
        float q0 = b2f((ushort_t)(qu & 0xffffu));
        float q1 = b2f((ushort_t)(qu >> 16));
        float sacc[8][2];
        float psum[8];
#pragma unroll
        for (int h = 0; h < 8; ++h) {
            sacc[h][0] = 0.f; sacc[h][1] = 0.f; psum[h] = 0.f;
        }
        int pos = rs;
        for (; pos + 2 <= re; pos += 2) {
            int e0 = eidx[pos], e1 = eidx[pos + 1];
            int s0 = src[e0], s1 = src[e1];
            float2 b0 = *(const float2*)&bond[(size_t)e0 * D + c0];
            float2 b1 = *(const float2*)&bond[(size_t)e1 * D + c0];
            unsigned k0u = *(const unsigned*)&kbf[(size_t)s0 * D + c0];
            unsigned k1u = *(const unsigned*)&kbf[(size_t)s1 * D + c0];
            float ba0 = basic[e0], ba1 = basic[e1];
            float part0 = q0 * b2f((ushort_t)(k0u & 0xffffu)) +
                          q1 * b2f((ushort_t)(k0u >> 16));
            float part1 = q0 * b2f((ushort_t)(k1u & 0xffffu)) +
                          q1 * b2f((ushort_t)(k1u >> 16));
            part0 += __shfl_xor(part0, 1);
            part1 += __shfl_xor(part1, 1);
            part0 += __shfl_xor(part0, 2);
            part1 += __shfl_xor(part1, 2);
            part0 += __shfl_xor(part0, 4);
            part1 += __shfl_xor(part1, 4);
            float p0 = expf(part0 * 0.25f + ba0 * wd);
            float p1 = expf(part1 * 0.25f + ba1 * wd);
#pragma unroll
            for (int h = 0; h < 8; ++h) {
                float ph0 = __shfl(p0, h * 8);
                float ph1 = __shfl(p1, h * 8);
                psum[h] += ph0 + ph1;
                sacc[h][0] += ph0 * b0.x + ph1 * b1.x;
                sacc[h][1] += ph0 * b0.y + ph1 * b1.y;
            }
        }
        for (; pos < re; ++pos) {
            int e = eidx[pos];
            int sc = src[e];
            float2 b = *(const float2*)&bond[(size_t)e * D + c0];
            unsigned ku = *(const unsigned*)&kbf[(size_t)sc * D + c0];
            float ba = basic[e];
            float part = q0 * b2f((ushort_t)(ku & 0xffffu)) +
                         q1 * b2f((ushort_t)(ku >> 16));
            part += __shfl_xor(part, 1);
            part += __shfl_xor(part, 2);
            part += __shfl_xor(part, 4);
            float p = expf(part * 0.25f + ba * wd);
#pragma unroll
            for (int h = 0; h < 8; ++h) {
                float ph = __shfl(p, h * 8);
                psum[h] += ph;
                sacc[h][0] += ph * b.x;
                sacc[h][1] += ph * b.y;
            }
        }
#pragma unroll
        for (int h = 0; h < 8; ++h) {
            float siv = (psum[h] > 0.f) ? 1.f / psum[h] : 0.f;
            unsigned u = (unsigned)(unsigned short)f2b(sacc[h][0] * siv) |
                         ((unsigned)(unsigned short)f2b(sacc[h][1] * siv) << 16);
            *(unsigned*)&slds[(h * 16 + ln) * 128 +
                              ((chunk ^ (ln & 7)) << 3) + elo] = u;
        }
    }
    __syncthreads();

    // ---- Phase B: projection. Wave w owns heads 2w, 2w+1. ----
    bf16x8 bfr[2][4];
#pragma unroll
    for (int nn = 0; nn < 2; ++nn) {
        int col = (2 * w + nn) * 16 + lr;
#pragma unroll
        for (int ks = 0; ks < 4; ++ks) {
            const float4* gp = (const float4*)(Wv + (size_t)col * D + ks * 32 + lg * 8);
            float4 f0 = gp[0], f1 = gp[1];
            bf16x8 v;
            v[0] = f2b(f0.x); v[1] = f2b(f0.y); v[2] = f2b(f0.z); v[3] = f2b(f0.w);
            v[4] = f2b(f1.x); v[5] = f2b(f1.y); v[6] = f2b(f1.z); v[7] = f2b(f1.w);
            bfr[nn][ks] = v;
        }
    }
    f32x4 acc[2];
#pragma unroll
    for (int nn = 0; nn < 2; ++nn) acc[nn] = (f32x4){0.f, 0.f, 0.f, 0.f};
#pragma unroll
    for (int ks = 0; ks < 4; ++ks) {
        int ck = ks * 4 + lg;
#pragma unroll
        for (int nn = 0; nn < 2; ++nn) {
            int h = 2 * w + nn;
            bf16x8 sf = *(const bf16x8*)&slds[(h * 16 + lr) * 128 +
                                              ((ck ^ (lr & 7)) << 3)];
            acc[nn] = __builtin_amdgcn_mfma_f32_16x16x32_bf16(
                bfr[nn][ks], sf, acc[nn], 0, 0, 0);  // swapped operands
        }
    }
#pragma unroll
    for (int nn = 0; nn < 2; ++nn) {
        float4 o = {acc[nn][0], acc[nn][1], acc[nn][2], acc[nn][3]};
        *(float4*)&ft[(size_t)(n0 + lr) * D + (2 * w + nn) * 16 + lg * 4] = o;
    }
}

// K5: MFMA node kernel. 32 nodes/block, 4 waves.
__global__ __launch_bounds__(256, 2) void k_node(
    const float* __restrict__ ft, const float* __restrict__ x,
    const float* __restrict__ Wb, const float* __restrict__ W1,
    const float* __restrict__ W2, const float* __restrict__ g_ln,
    const float* __restrict__ b_ln, float* __restrict__ out) {
    __shared__ float hs[NPB][132];
    __shared__ short hA[NPB * 128];
    __shared__ short hid[NPB * 256];
    __shared__ float ylds[NPB][132];
    const int t = threadIdx.x;
    const int lane = t & 63, w = t >> 6;
    const int lr = lane & 15, lg = lane >> 4;
    const int n0 = blockIdx.x * NPB;
    const int c0 = lane * 2;

    const float2 wb0 = *(const float2*)&Wb[c0];
    const float2 wb1 = *(const float2*)&Wb[128 + c0];
    const float2 wb2 = *(const float2*)&Wb[256 + c0];
    const float2 gv = *(const float2*)&g_ln[c0];
    const float2 bv = *(const float2*)&b_ln[c0];
#pragma unroll
    for (int i = 0; i < 8; ++i) {
        int n = w * 8 + i;
        int gn = n0 + n;
        float2 fv = {0.f, 0.f}, xv = {0.f, 0.f};
        if (gn < N_NODES) {
            fv = *(const float2*)&ft[(size_t)gn * D + c0];
            xv = *(const float2*)&x[(size_t)gn * D + c0];
        }
        float part = fv.x * wb0.x + fv.y * wb0.y + xv.x * wb1.x + xv.y * wb1.y +
                     (fv.x - xv.x) * wb2.x + (fv.y - xv.y) * wb2.y;
        float beta = 1.f / (1.f + expf(-wred(part)));
        float hex = beta * xv.x + (1.f - beta) * fv.x;
        float hey = beta * xv.y + (1.f - beta) * fv.y;
        hs[n][c0] = hex;
        hs[n][c0 + 1] = hey;
        float mu = wred(hex + hey) * (1.f / 128.f);
        float dx = hex - mu, dy = hey - mu;
        float var = wred(dx * dx + dy * dy) * (1.f / 128.f);
        float rs = rsqrtf(var + LN_EPS);
        float h0 = dx * rs * gv.x + bv.x;
        float h1 = dy * rs * gv.y + bv.y;
        unsigned u = (unsigned)(unsigned short)f2b(h0) |
                     ((unsigned)(unsigned short)f2b(h1) << 16);
        int phys = (lane >> 2) ^ (n & 7);
        ((unsigned*)hA)[n * 64 + phys * 4 + (lane & 3)] = u;
    }
    __syncthreads();

    {
        bf16x8 b1[4][4];
#pragma unroll
        for (int nt = 0; nt < 4; ++nt) {
            int col = w * 64 + nt * 16 + lr;
#pragma unroll
            for (int ks = 0; ks < 4; ++ks) {
                const float4* gp = (const float4*)(W1 + (size_t)col * D + ks * 32 + lg * 8);
                float4 f0 = gp[0], f1 = gp[1];
                bf16x8 v;
                v[0] = f2b(f0.x); v[1] = f2b(f0.y); v[2] = f2b(f0.z); v[3] = f2b(f0.w);
                v[4] = f2b(f1.x); v[5] = f2b(f1.y); v[6] = f2b(f1.z); v[7] = f2b(f1.w);
                b1[nt][ks] = v;
            }
        }
        f32x4 acc1[2][4];
#pragma unroll
        for (int m = 0; m < 2; ++m)
#pragma unroll
            for (int nt = 0; nt < 4; ++nt) acc1[m][nt] = (f32x4){0.f, 0.f, 0.f, 0.f};
#pragma unroll
        for (int ks = 0; ks < 4; ++ks) {
            int chunk = ks * 4 + lg;
#pragma unroll
            for (int m = 0; m < 2; ++m) {
                int row = m * 16 + lr;
                bf16x8 af = *(const bf16x8*)&hA[row * 128 + ((chunk ^ (row & 7)) << 3)];
#pragma unroll
                for (int nt = 0; nt < 4; ++nt)
                    acc1[m][nt] = __builtin_amdgcn_mfma_f32_16x16x32_bf16(
                        af, b1[nt][ks], acc1[m][nt], 0, 0, 0);
            }
        }
#pragma unroll
        for (int m = 0; m < 2; ++m)
#pragma unroll
            for (int nt = 0; nt < 4; ++nt)
#pragma unroll
                for (int r = 0; r < 4; ++r) {
                    int node = m * 16 + lg * 4 + r;
                    int col = w * 64 + nt * 16 + lr;
                    float v = fmaxf(acc1[m][nt][r], 0.f);
                    hid[node * 256 + (((col >> 3) ^ (node & 7)) << 3) + (col & 7)] = f2b(v);
                }
    }
    __syncthreads();

    {
        bf16x8 b2[2][8];
#pragma unroll
        for (int nt = 0; nt < 2; ++nt) {
            int col = w * 32 + nt * 16 + lr;
#pragma unroll
            for (int ks = 0; ks < 8; ++ks) {
                const float4* gp = (const float4*)(W2 + (size_t)col * DFF + ks * 32 + lg * 8);
                float4 f0 = gp[0], f1 = gp[1];
                bf16x8 v;
                v[0] = f2b(f0.x); v[1] = f2b(f0.y); v[2] = f2b(f0.z); v[3] = f2b(f0.w);
                v[4] = f2b(f1.x); v[5] = f2b(f1.y); v[6] = f2b(f1.z); v[7] = f2b(f1.w);
                b2[nt][ks] = v;
            }
        }
        f32x4 acc2[2][2];
#pragma unroll
        for (int m = 0; m < 2; ++m)
#pragma unroll
            for (int nt = 0; nt < 2; ++nt) acc2[m][nt] = (f32x4){0.f, 0.f, 0.f, 0.f};
#pragma unroll
        for (int ks = 0; ks < 8; ++ks) {
            int chunk = ks * 4 + lg;
#pragma unroll
            for (int m = 0; m < 2; ++m) {
                int row = m * 16 + lr;
                bf16x8 af = *(const bf16x8*)&hid[row * 256 + ((chunk ^ (row & 7)) << 3)];
#pragma unroll
                for (int nt = 0; nt < 2; ++nt)
                    acc2[m][nt] = __builtin_amdgcn_mfma_f32_16x16x32_bf16(
                        af, b2[nt][ks], acc2[m][nt], 0, 0, 0);
            }
        }
#pragma unroll
        for (int m = 0; m < 2; ++m)
#pragma unroll
            for (int nt = 0; nt < 2; ++nt)
#pragma unroll
                for (int r = 0; r < 4; ++r) {
                    int node = m * 16 + lg * 4 + r;
                    int col = w * 32 + nt * 16 + lr;
                    ylds[node][col] = acc2[m][nt][r] + hs[node][col];
                }
    }
    __syncthreads();

#pragma unroll
    for (int i = 0; i < 8; ++i) {
        int n = w * 8 + i;
        int gn = n0 + n;
        float y0 = ylds[n][c0], y1 = ylds[n][c0 + 1];
        float mu = wred(y0 + y1) * (1.f / 128.f);
        float d0 = y0 - mu, d1 = y1 - mu;
        float var = wred(d0 * d0 + d1 * d1) * (1.f / 128.f);
        float rs = rsqrtf(var + LN_EPS);
        if (gn < N_NODES) {
            float2 o = {d0 * rs, d1 * rs};
            *(float2*)&out[(size_t)gn * D + c0] = o;
        }
    }
}

extern "C" void kernel_launch(void* const* d_in, const int* in_sizes, int n_in,
                              void* d_out, int out_size, void* d_ws, size_t ws_size,
                              hipStream_t stream) {
    const float* bond = (const float*)d_in[0];
    const float* x    = (const float*)d_in[1];
    const float* basic= (const float*)d_in[2];
    const float* Wk   = (const float*)d_in[3];
    const float* Wq   = (const float*)d_in[4];
    const float* Wv   = (const float*)d_in[5];
    const float* Wdis = (const float*)d_in[6];
    const float* Wb   = (const float*)d_in[7];
    const float* W1   = (const float*)d_in[8];
    const float* W2   = (const float*)d_in[9];
    const float* g_ln = (const float*)d_in[10];
    const float* b_ln = (const float*)d_in[11];
    const int* src    = (const int*)d_in[12];
    const int* dst    = (const int*)d_in[13];
    float* out = (float*)d_out;

    // ws layout (~60 MB):
    ushort_t* kbf = (ushort_t*)d_ws;                    // N*128 bf16
    ushort_t* qbf = kbf + (size_t)N_NODES * D;          // N*128 bf16
    float* ftb   = (float*)(qbf + (size_t)N_NODES * D); // N*128 f32
    int* deg     = (int*)(ftb + (size_t)N_NODES * D);   // N [zeroed by k_zero]
    int* scanout = deg + N_NODES;                       // N
    int* bsum    = scanout + N_NODES;                   // 128
    int* rowstart= bsum + 128;                          // N+1
    int* cursor  = rowstart + N_NODES + 1;              // N
    int* eidx    = cursor + N_NODES;                    // E

    k_zero<<<(N_NODES + 255) / 256, 256, 0, stream>>>(deg);
    k_qkproj<<<N_NODES / 16, 128, 0, stream>>>(x, Wk, Wq, kbf, qbf);
    k_hist<<<N_EDGES / 256, 256, 0, stream>>>(dst, deg);
    k_scan1<<<NSCAN, SCAN_BS, 0, stream>>>(deg, scanout, bsum);
    k_scan2<<<1, 128, 0, stream>>>(bsum);
    k_scan3<<<(N_NODES + 255) / 256, 256, 0, stream>>>(scanout, bsum, rowstart, cursor);
    k_fill<<<N_EDGES / 256, 256, 0, stream>>>(dst, cursor, eidx);
    k_hsum<<<N_NODES / GN, 256, 0, stream>>>(bond, kbf, qbf, basic, Wdis, src,
                                             Wv, rowstart, eidx, ftb);
    k_node<<<(N_NODES + NPB - 1) / NPB, 256, 0, stream>>>(ftb, x, Wb, W1, W2,
                                                          g_ln, b_ln, out);
}

// Round 17
// 490.598 us; speedup vs baseline: 1.1351x; 1.1351x over previous
//
#include <hip/hip_runtime.h>
#include <hip/hip_bf16.h>

#define N_NODES 50000
#define N_EDGES 800000
#define D 128
#define NH 8
#define DH 16
#define DFF 256
#define LN_EPS 1e-5f
#define GN 16
#define NPB 32
#define SCAN_BS 512
#define NSCAN ((N_NODES + SCAN_BS - 1) / SCAN_BS)  // 98

typedef __attribute__((ext_vector_type(8))) short bf16x8;
typedef __attribute__((ext_vector_type(8))) unsigned short u16x8;
typedef __attribute__((ext_vector_type(4))) float f32x4;
typedef unsigned short ushort_t;

__device__ __forceinline__ float wred(float v) {
#pragma unroll
    for (int o = 32; o; o >>= 1) v += __shfl_xor(v, o);
    return v;
}

// fp32 -> bf16 (RNE) bit helper
__device__ __forceinline__ short f2b(float f) {
    unsigned u = __float_as_uint(f);
    unsigned r = u + 0x7fffu + ((u >> 16) & 1u);
    return (short)(r >> 16);
}
__device__ __forceinline__ float b2f(unsigned short u) {
    return __uint_as_float((unsigned)u << 16);
}

// K0: zero the degree array.
__global__ __launch_bounds__(256) void k_zero(int* __restrict__ p) {
    int i = blockIdx.x * 256 + threadIdx.x;
    if (i < N_NODES) p[i] = 0;
}

// K1: q/k projections -> bf16. 16 nodes per 128-thread block.
__global__ __launch_bounds__(128) void k_qkproj(
    const float* __restrict__ x, const float* __restrict__ Wk,
    const float* __restrict__ Wq, ushort_t* __restrict__ kout,
    ushort_t* __restrict__ qout) {
    __shared__ float xs[16][128];
    const int t = threadIdx.x;
    const int nb = blockIdx.x * 16;
#pragma unroll
    for (int r = 0; r < 16; ++r) xs[r][t] = x[(size_t)(nb + r) * D + t];
    __syncthreads();
    const float4* wk4 = (const float4*)(Wk + (size_t)t * D);
    const float4* wq4 = (const float4*)(Wq + (size_t)t * D);
    float ka[16] = {}, qa[16] = {};
#pragma unroll 4
    for (int i4 = 0; i4 < 32; ++i4) {
        float4 wk = wk4[i4], wq = wq4[i4];
#pragma unroll
        for (int r = 0; r < 16; ++r) {
            float4 xv = *(const float4*)&xs[r][i4 * 4];
            ka[r] += wk.x * xv.x + wk.y * xv.y + wk.z * xv.z + wk.w * xv.w;
            qa[r] += wq.x * xv.x + wq.y * xv.y + wq.z * xv.z + wq.w * xv.w;
        }
    }
#pragma unroll
    for (int r = 0; r < 16; ++r) {
        kout[(size_t)(nb + r) * D + t] = (ushort_t)f2b(ka[r]);
        qout[(size_t)(nb + r) * D + t] = (ushort_t)f2b(qa[r]);
    }
}

// CSR build ---------------------------------------------------------------
__global__ __launch_bounds__(256) void k_hist(const int* __restrict__ dst,
                                              int* __restrict__ deg) {
    int e = blockIdx.x * 256 + threadIdx.x;
    atomicAdd(&deg[dst[e]], 1);
}

__global__ __launch_bounds__(SCAN_BS) void k_scan1(
    const int* __restrict__ deg, int* __restrict__ scanout,
    int* __restrict__ bsum) {
    __shared__ int ss[SCAN_BS];
    const int t = threadIdx.x;
    const int i = blockIdx.x * SCAN_BS + t;
    int v = (i < N_NODES) ? deg[i] : 0;
    ss[t] = v;
    __syncthreads();
    for (int off = 1; off < SCAN_BS; off <<= 1) {
        int a = (t >= off) ? ss[t - off] : 0;
        __syncthreads();
        ss[t] += a;
        __syncthreads();
    }
    if (i < N_NODES) scanout[i] = ss[t] - v;
    if (t == SCAN_BS - 1) bsum[blockIdx.x] = ss[t];
}

__global__ __launch_bounds__(128) void k_scan2(int* __restrict__ bsum) {
    __shared__ int ss[128];
    const int t = threadIdx.x;
    int v = (t < NSCAN) ? bsum[t] : 0;
    ss[t] = v;
    __syncthreads();
    for (int off = 1; off < 128; off <<= 1) {
        int a = (t >= off) ? ss[t - off] : 0;
        __syncthreads();
        ss[t] += a;
        __syncthreads();
    }
    if (t < NSCAN) bsum[t] = ss[t] - v;
}

__global__ __launch_bounds__(256) void k_scan3(
    const int* __restrict__ scanout, const int* __restrict__ bsum,
    int* __restrict__ rowstart, int* __restrict__ cursor) {
    int i = blockIdx.x * 256 + threadIdx.x;
    if (i < N_NODES) {
        int rs = scanout[i] + bsum[i / SCAN_BS];
        rowstart[i] = rs;
        cursor[i] = rs;
    }
    if (i == 0) rowstart[N_NODES] = N_EDGES;
}

__global__ __launch_bounds__(256) void k_fill(const int* __restrict__ dst,
                                              int* __restrict__ cursor,
                                              int* __restrict__ eidx) {
    int e = blockIdx.x * 256 + threadIdx.x;
    int pos = atomicAdd(&cursor[dst[e]], 1);
    eidx[pos] = e;
}

// K2: fused logits+softmax, SINGLE edge pass (r15-proven).
__global__ __launch_bounds__(256) void k_attn(
    const ushort_t* __restrict__ kv, const ushort_t* __restrict__ qv,
    const float* __restrict__ basic, const float* __restrict__ Wdis,
    const int* __restrict__ src, const int* __restrict__ rowstart,
    const int* __restrict__ eidx, float* __restrict__ aperm,
    float* __restrict__ sinv) {
    const int t = threadIdx.x;
    const int lane = t & 63, wv = t >> 6;
    const int n = blockIdx.x * 4 + wv;
    const int j = lane >> 3, h = lane & 7;
    const int rs = rowstart[n], re = rowstart[n + 1];
    const float wd = Wdis[h];
    const ushort_t* qp = qv + (size_t)n * D + h * DH;
    u16x8 q0 = *(const u16x8*)qp;
    u16x8 q1 = *(const u16x8*)(qp + 8);
    float qf[16];
#pragma unroll
    for (int i = 0; i < 8; ++i) { qf[i] = b2f(q0[i]); qf[8 + i] = b2f(q1[i]); }

    float sl = 0.f;
    for (int base = rs; base < re; base += 8) {
        int pos = base + j;
        if (pos < re) {
            int e = eidx[pos];
            int sc = src[e];
            const ushort_t* kp = kv + (size_t)sc * D + h * DH;
            u16x8 k0 = *(const u16x8*)kp;
            u16x8 k1 = *(const u16x8*)(kp + 8);
            float acc = 0.f;
#pragma unroll
            for (int i = 0; i < 8; ++i) acc += qf[i] * b2f(k0[i]);
#pragma unroll
            for (int i = 0; i < 8; ++i) acc += qf[8 + i] * b2f(k1[i]);
            float p = expf(acc * 0.25f + basic[e] * wd);
            aperm[(size_t)pos * NH + h] = p;
            sl += p;
        }
    }
    sl += __shfl_xor(sl, 8);
    sl += __shfl_xor(sl, 16);
    sl += __shfl_xor(sl, 32);
    if (lane < 8) sinv[(size_t)n * NH + h] = (sl > 0.f) ? 1.f / sl : 0.f;
}

// K3: fused per-head weighted-sum + projection (r15 structure, 4-deep unroll).
// ft_n[h*16+j] = sinv_{n,h} * Wv[h*16+j,:] . (sum_e p_{e,h} * bond_e)
__global__ __launch_bounds__(256) void k_hsum(
    const float* __restrict__ bond, const float* __restrict__ Wv,
    const float* __restrict__ aperm, const float* __restrict__ sinv,
    const int* __restrict__ rowstart, const int* __restrict__ eidx,
    float* __restrict__ ft) {
    __shared__ short slds[8 * 16 * 128];  // [head][node][k] bf16, swizzled
    __shared__ float sivlds[GN * 8];
    __shared__ int srs[GN + 1];
    const int t = threadIdx.x;
    const int lane = t & 63, w = t >> 6;
    const int lr = lane & 15, lg = lane >> 4;
    const int n0 = blockIdx.x * GN;
    if (t < GN + 1) srs[t] = rowstart[n0 + t];
    if (t < GN * 8) sivlds[t] = sinv[(size_t)n0 * 8 + t];
    __syncthreads();

    const int c0 = lane * 2;
    const int chunk = lane >> 2;
    const int elo = (lane * 2) & 7;

    // ---- Phase A: each wave owns nodes w, w+4, w+8, w+12 ----
#pragma unroll
    for (int i = 0; i < 4; ++i) {
        int ln = w + i * 4;
        int rs = srs[ln], re = srs[ln + 1];
        float sacc[8][2];
#pragma unroll
        for (int h = 0; h < 8; ++h) { sacc[h][0] = 0.f; sacc[h][1] = 0.f; }
        int pos = rs;
        // 4-deep unroll: 4 independent eidx->bond gather chains in flight.
        for (; pos + 4 <= re; pos += 4) {
            int e0 = eidx[pos], e1 = eidx[pos + 1];
            int e2 = eidx[pos + 2], e3 = eidx[pos + 3];
            float2 b0 = *(const float2*)&bond[(size_t)e0 * D + c0];
            float2 b1 = *(const float2*)&bond[(size_t)e1 * D + c0];
            float2 b2 = *(const float2*)&bond[(size_t)e2 * D + c0];
            float2 b3 = *(const float2*)&bond[(size_t)e3 * D + c0];
            float4 a00 = *(const float4*)&aperm[(size_t)pos * 8];
            float4 a01 = *(const float4*)&aperm[(size_t)pos * 8 + 4];
            float4 a10 = *(const float4*)&aperm[(size_t)(pos + 1) * 8];
            float4 a11 = *(const float4*)&aperm[(size_t)(pos + 1) * 8 + 4];
            float4 a20 = *(const float4*)&aperm[(size_t)(pos + 2) * 8];
            float4 a21 = *(const float4*)&aperm[(size_t)(pos + 2) * 8 + 4];
            float4 a30 = *(const float4*)&aperm[(size_t)(pos + 3) * 8];
            float4 a31 = *(const float4*)&aperm[(size_t)(pos + 3) * 8 + 4];
            const float a0v[8] = {a00.x, a00.y, a00.z, a00.w,
                                  a01.x, a01.y, a01.z, a01.w};
            const float a1v[8] = {a10.x, a10.y, a10.z, a10.w,
                                  a11.x, a11.y, a11.z, a11.w};
            const float a2v[8] = {a20.x, a20.y, a20.z, a20.w,
                                  a21.x, a21.y, a21.z, a21.w};
            const float a3v[8] = {a30.x, a30.y, a30.z, a30.w,
                                  a31.x, a31.y, a31.z, a31.w};
#pragma unroll
            for (int h = 0; h < 8; ++h) {
                sacc[h][0] += a0v[h] * b0.x + a1v[h] * b1.x +
                              a2v[h] * b2.x + a3v[h] * b3.x;
                sacc[h][1] += a0v[h] * b0.y + a1v[h] * b1.y +
                              a2v[h] * b2.y + a3v[h] * b3.y;
            }
        }
        for (; pos < re; ++pos) {
            int e = eidx[pos];
            float2 b = *(const float2*)&bond[(size_t)e * D + c0];
            float4 a0 = *(const float4*)&aperm[(size_t)pos * 8];
            float4 a1 = *(const float4*)&aperm[(size_t)pos * 8 + 4];
            const float av[8] = {a0.x, a0.y, a0.z, a0.w,
                                 a1.x, a1.y, a1.z, a1.w};
#pragma unroll
            for (int h = 0; h < 8; ++h) {
                sacc[h][0] += av[h] * b.x;
                sacc[h][1] += av[h] * b.y;
            }
        }
#pragma unroll
        for (int h = 0; h < 8; ++h) {
            float siv = sivlds[ln * 8 + h];
            unsigned u = (unsigned)(unsigned short)f2b(sacc[h][0] * siv) |
                         ((unsigned)(unsigned short)f2b(sacc[h][1] * siv) << 16);
            *(unsigned*)&slds[(h * 16 + ln) * 128 +
                              ((chunk ^ (ln & 7)) << 3) + elo] = u;
        }
    }
    __syncthreads();

    // ---- Phase B: projection. Wave w owns heads 2w, 2w+1. ----
    bf16x8 bfr[2][4];
#pragma unroll
    for (int nn = 0; nn < 2; ++nn) {
        int col = (2 * w + nn) * 16 + lr;
#pragma unroll
        for (int ks = 0; ks < 4; ++ks) {
            const float4* gp = (const float4*)(Wv + (size_t)col * D + ks * 32 + lg * 8);
            float4 f0 = gp[0], f1 = gp[1];
            bf16x8 v;
            v[0] = f2b(f0.x); v[1] = f2b(f0.y); v[2] = f2b(f0.z); v[3] = f2b(f0.w);
            v[4] = f2b(f1.x); v[5] = f2b(f1.y); v[6] = f2b(f1.z); v[7] = f2b(f1.w);
            bfr[nn][ks] = v;
        }
    }
    f32x4 acc[2];
#pragma unroll
    for (int nn = 0; nn < 2; ++nn) acc[nn] = (f32x4){0.f, 0.f, 0.f, 0.f};
#pragma unroll
    for (int ks = 0; ks < 4; ++ks) {
        int ck = ks * 4 + lg;
#pragma unroll
        for (int nn = 0; nn < 2; ++nn) {
            int h = 2 * w + nn;
            bf16x8 sf = *(const bf16x8*)&slds[(h * 16 + lr) * 128 +
                                              ((ck ^ (lr & 7)) << 3)];
            acc[nn] = __builtin_amdgcn_mfma_f32_16x16x32_bf16(
                bfr[nn][ks], sf, acc[nn], 0, 0, 0);  // swapped operands
        }
    }
#pragma unroll
    for (int nn = 0; nn < 2; ++nn) {
        float4 o = {acc[nn][0], acc[nn][1], acc[nn][2], acc[nn][3]};
        *(float4*)&ft[(size_t)(n0 + lr) * D + (2 * w + nn) * 16 + lg * 4] = o;
    }
}

// K5: MFMA node kernel. 32 nodes/block, 4 waves.
__global__ __launch_bounds__(256, 2) void k_node(
    const float* __restrict__ ft, const float* __restrict__ x,
    const float* __restrict__ Wb, const float* __restrict__ W1,
    const float* __restrict__ W2, const float* __restrict__ g_ln,
    const float* __restrict__ b_ln, float* __restrict__ out) {
    __shared__ float hs[NPB][132];
    __shared__ short hA[NPB * 128];
    __shared__ short hid[NPB * 256];
    __shared__ float ylds[NPB][132];
    const int t = threadIdx.x;
    const int lane = t & 63, w = t >> 6;
    const int lr = lane & 15, lg = lane >> 4;
    const int n0 = blockIdx.x * NPB;
    const int c0 = lane * 2;

    const float2 wb0 = *(const float2*)&Wb[c0];
    const float2 wb1 = *(const float2*)&Wb[128 + c0];
    const float2 wb2 = *(const float2*)&Wb[256 + c0];
    const float2 gv = *(const float2*)&g_ln[c0];
    const float2 bv = *(const float2*)&b_ln[c0];
#pragma unroll
    for (int i = 0; i < 8; ++i) {
        int n = w * 8 + i;
        int gn = n0 + n;
        float2 fv = {0.f, 0.f}, xv = {0.f, 0.f};
        if (gn < N_NODES) {
            fv = *(const float2*)&ft[(size_t)gn * D + c0];
            xv = *(const float2*)&x[(size_t)gn * D + c0];
        }
        float part = fv.x * wb0.x + fv.y * wb0.y + xv.x * wb1.x + xv.y * wb1.y +
                     (fv.x - xv.x) * wb2.x + (fv.y - xv.y) * wb2.y;
        float beta = 1.f / (1.f + expf(-wred(part)));
        float hex = beta * xv.x + (1.f - beta) * fv.x;
        float hey = beta * xv.y + (1.f - beta) * fv.y;
        hs[n][c0] = hex;
        hs[n][c0 + 1] = hey;
        float mu = wred(hex + hey) * (1.f / 128.f);
        float dx = hex - mu, dy = hey - mu;
        float var = wred(dx * dx + dy * dy) * (1.f / 128.f);
        float rs = rsqrtf(var + LN_EPS);
        float h0 = dx * rs * gv.x + bv.x;
        float h1 = dy * rs * gv.y + bv.y;
        unsigned u = (unsigned)(unsigned short)f2b(h0) |
                     ((unsigned)(unsigned short)f2b(h1) << 16);
        int phys = (lane >> 2) ^ (n & 7);
        ((unsigned*)hA)[n * 64 + phys * 4 + (lane & 3)] = u;
    }
    __syncthreads();

    {
        bf16x8 b1[4][4];
#pragma unroll
        for (int nt = 0; nt < 4; ++nt) {
            int col = w * 64 + nt * 16 + lr;
#pragma unroll
            for (int ks = 0; ks < 4; ++ks) {
                const float4* gp = (const float4*)(W1 + (size_t)col * D + ks * 32 + lg * 8);
                float4 f0 = gp[0], f1 = gp[1];
                bf16x8 v;
                v[0] = f2b(f0.x); v[1] = f2b(f0.y); v[2] = f2b(f0.z); v[3] = f2b(f0.w);
                v[4] = f2b(f1.x); v[5] = f2b(f1.y); v[6] = f2b(f1.z); v[7] = f2b(f1.w);
                b1[nt][ks] = v;
            }
        }
        f32x4 acc1[2][4];
#pragma unroll
        for (int m = 0; m < 2; ++m)
#pragma unroll
            for (int nt = 0; nt < 4; ++nt) acc1[m][nt] = (f32x4){0.f, 0.f, 0.f, 0.f};
#pragma unroll
        for (int ks = 0; ks < 4; ++ks) {
            int chunk = ks * 4 + lg;
#pragma unroll
            for (int m = 0; m < 2; ++m) {
                int row = m * 16 + lr;
                bf16x8 af = *(const bf16x8*)&hA[row * 128 + ((chunk ^ (row & 7)) << 3)];
#pragma unroll
                for (int nt = 0; nt < 4; ++nt)
                    acc1[m][nt] = __builtin_amdgcn_mfma_f32_16x16x32_bf16(
                        af, b1[nt][ks], acc1[m][nt], 0, 0, 0);
            }
        }
#pragma unroll
        for (int m = 0; m < 2; ++m)
#pragma unroll
            for (int nt = 0; nt < 4; ++nt)
#pragma unroll
                for (int r = 0; r < 4; ++r) {
                    int node = m * 16 + lg * 4 + r;
                    int col = w * 64 + nt * 16 + lr;
                    float v = fmaxf(acc1[m][nt][r], 0.f);
                    hid[node * 256 + (((col >> 3) ^ (node & 7)) << 3) + (col & 7)] = f2b(v);
                }
    }
    __syncthreads();

    {
        bf16x8 b2[2][8];
#pragma unroll
        for (int nt = 0; nt < 2; ++nt) {
            int col = w * 32 + nt * 16 + lr;
#pragma unroll
            for (int ks = 0; ks < 8; ++ks) {
                const float4* gp = (const float4*)(W2 + (size_t)col * DFF + ks * 32 + lg * 8);
                float4 f0 = gp[0], f1 = gp[1];
                bf16x8 v;
                v[0] = f2b(f0.x); v[1] = f2b(f0.y); v[2] = f2b(f0.z); v[3] = f2b(f0.w);
                v[4] = f2b(f1.x); v[5] = f2b(f1.y); v[6] = f2b(f1.z); v[7] = f2b(f1.w);
                b2[nt][ks] = v;
            }
        }
        f32x4 acc2[2][2];
#pragma unroll
        for (int m = 0; m < 2; ++m)
#pragma unroll
            for (int nt = 0; nt < 2; ++nt) acc2[m][nt] = (f32x4){0.f, 0.f, 0.f, 0.f};
#pragma unroll
        for (int ks = 0; ks < 8; ++ks) {
            int chunk = ks * 4 + lg;
#pragma unroll
            for (int m = 0; m < 2; ++m) {
                int row = m * 16 + lr;
                bf16x8 af = *(const bf16x8*)&hid[row * 256 + ((chunk ^ (row & 7)) << 3)];
#pragma unroll
                for (int nt = 0; nt < 2; ++nt)
                    acc2[m][nt] = __builtin_amdgcn_mfma_f32_16x16x32_bf16(
                        af, b2[nt][ks], acc2[m][nt], 0, 0, 0);
            }
        }
#pragma unroll
        for (int m = 0; m < 2; ++m)
#pragma unroll
            for (int nt = 0; nt < 2; ++nt)
#pragma unroll
                for (int r = 0; r < 4; ++r) {
                    int node = m * 16 + lg * 4 + r;
                    int col = w * 32 + nt * 16 + lr;
                    ylds[node][col] = acc2[m][nt][r] + hs[node][col];
                }
    }
    __syncthreads();

#pragma unroll
    for (int i = 0; i < 8; ++i) {
        int n = w * 8 + i;
        int gn = n0 + n;
        float y0 = ylds[n][c0], y1 = ylds[n][c0 + 1];
        float mu = wred(y0 + y1) * (1.f / 128.f);
        float d0 = y0 - mu, d1 = y1 - mu;
        float var = wred(d0 * d0 + d1 * d1) * (1.f / 128.f);
        float rs = rsqrtf(var + LN_EPS);
        if (gn < N_NODES) {
            float2 o = {d0 * rs, d1 * rs};
            *(float2*)&out[(size_t)gn * D + c0] = o;
        }
    }
}

extern "C" void kernel_launch(void* const* d_in, const int* in_sizes, int n_in,
                              void* d_out, int out_size, void* d_ws, size_t ws_size,
                              hipStream_t stream) {
    const float* bond = (const float*)d_in[0];
    const float* x    = (const float*)d_in[1];
    const float* basic= (const float*)d_in[2];
    const float* Wk   = (const float*)d_in[3];
    const float* Wq   = (const float*)d_in[4];
    const float* Wv   = (const float*)d_in[5];
    const float* Wdis = (const float*)d_in[6];
    const float* Wb   = (const float*)d_in[7];
    const float* W1   = (const float*)d_in[8];
    const float* W2   = (const float*)d_in[9];
    const float* g_ln = (const float*)d_in[10];
    const float* b_ln = (const float*)d_in[11];
    const int* src    = (const int*)d_in[12];
    const int* dst    = (const int*)d_in[13];
    float* out = (float*)d_out;

    // ws layout (~86 MB):
    ushort_t* kbf = (ushort_t*)d_ws;                    // N*128 bf16
    ushort_t* qbf = kbf + (size_t)N_NODES * D;          // N*128 bf16
    float* aperm = (float*)(qbf + (size_t)N_NODES * D); // E*8 f32 (unnorm p)
    float* ftb   = aperm + (size_t)N_EDGES * NH;        // N*128 f32
    float* sinvb = ftb + (size_t)N_NODES * D;           // N*8 f32
    int* deg     = (int*)(sinvb + (size_t)N_NODES * NH);// N [zeroed by k_zero]
    int* scanout = deg + N_NODES;                       // N
    int* bsum    = scanout + N_NODES;                   // 128
    int* rowstart= bsum + 128;                          // N+1
    int* cursor  = rowstart + N_NODES + 1;              // N
    int* eidx    = cursor + N_NODES;                    // E

    k_zero<<<(N_NODES + 255) / 256, 256, 0, stream>>>(deg);
    k_qkproj<<<N_NODES / 16, 128, 0, stream>>>(x, Wk, Wq, kbf, qbf);
    k_hist<<<N_EDGES / 256, 256, 0, stream>>>(dst, deg);
    k_scan1<<<NSCAN, SCAN_BS, 0, stream>>>(deg, scanout, bsum);
    k_scan2<<<1, 128, 0, stream>>>(bsum);
    k_scan3<<<(N_NODES + 255) / 256, 256, 0, stream>>>(scanout, bsum, rowstart, cursor);
    k_fill<<<N_EDGES / 256, 256, 0, stream>>>(dst, cursor, eidx);
    k_attn<<<N_NODES / 4, 256, 0, stream>>>(kbf, qbf, basic, Wdis, src,
                                            rowstart, eidx, aperm, sinvb);
    k_hsum<<<N_NODES / GN, 256, 0, stream>>>(bond, Wv, aperm, sinvb,
                                             rowstart, eidx, ftb);
    k_node<<<(N_NODES + NPB - 1) / NPB, 256, 0, stream>>>(ftb, x, Wb, W1, W2,
                                                          g_ln, b_ln, out);
}

// Round 18
// 488.735 us; speedup vs baseline: 1.1394x; 1.0038x over previous
//
#include <hip/hip_runtime.h>
#include <hip/hip_bf16.h>

#define N_NODES 50000
#define N_EDGES 800000
#define D 128
#define NH 8
#define DH 16
#define DFF 256
#define LN_EPS 1e-5f
#define GN 16
#define NPB 32
#define SCAN_BS 512
#define NSCAN ((N_NODES + SCAN_BS - 1) / SCAN_BS)  // 98

typedef __attribute__((ext_vector_type(8))) short bf16x8;
typedef __attribute__((ext_vector_type(8))) unsigned short u16x8;
typedef __attribute__((ext_vector_type(4))) float f32x4;
typedef unsigned short ushort_t;

__device__ __forceinline__ float wred(float v) {
#pragma unroll
    for (int o = 32; o; o >>= 1) v += __shfl_xor(v, o);
    return v;
}

// fp32 -> bf16 (RNE) bit helper
__device__ __forceinline__ short f2b(float f) {
    unsigned u = __float_as_uint(f);
    unsigned r = u + 0x7fffu + ((u >> 16) & 1u);
    return (short)(r >> 16);
}
__device__ __forceinline__ float b2f(unsigned short u) {
    return __uint_as_float((unsigned)u << 16);
}

// K0: zero the degree array.
__global__ __launch_bounds__(256) void k_zero(int* __restrict__ p) {
    int i = blockIdx.x * 256 + threadIdx.x;
    if (i < N_NODES) p[i] = 0;
}

// K1: q/k projections -> bf16. 16 nodes per 128-thread block.
__global__ __launch_bounds__(128) void k_qkproj(
    const float* __restrict__ x, const float* __restrict__ Wk,
    const float* __restrict__ Wq, ushort_t* __restrict__ kout,
    ushort_t* __restrict__ qout) {
    __shared__ float xs[16][128];
    const int t = threadIdx.x;
    const int nb = blockIdx.x * 16;
#pragma unroll
    for (int r = 0; r < 16; ++r) xs[r][t] = x[(size_t)(nb + r) * D + t];
    __syncthreads();
    const float4* wk4 = (const float4*)(Wk + (size_t)t * D);
    const float4* wq4 = (const float4*)(Wq + (size_t)t * D);
    float ka[16] = {}, qa[16] = {};
#pragma unroll 4
    for (int i4 = 0; i4 < 32; ++i4) {
        float4 wk = wk4[i4], wq = wq4[i4];
#pragma unroll
        for (int r = 0; r < 16; ++r) {
            float4 xv = *(const float4*)&xs[r][i4 * 4];
            ka[r] += wk.x * xv.x + wk.y * xv.y + wk.z * xv.z + wk.w * xv.w;
            qa[r] += wq.x * xv.x + wq.y * xv.y + wq.z * xv.z + wq.w * xv.w;
        }
    }
#pragma unroll
    for (int r = 0; r < 16; ++r) {
        kout[(size_t)(nb + r) * D + t] = (ushort_t)f2b(ka[r]);
        qout[(size_t)(nb + r) * D + t] = (ushort_t)f2b(qa[r]);
    }
}

// CSR build ---------------------------------------------------------------
__global__ __launch_bounds__(256) void k_hist(const int* __restrict__ dst,
                                              int* __restrict__ deg) {
    int e = blockIdx.x * 256 + threadIdx.x;
    atomicAdd(&deg[dst[e]], 1);
}

__global__ __launch_bounds__(SCAN_BS) void k_scan1(
    const int* __restrict__ deg, int* __restrict__ scanout,
    int* __restrict__ bsum) {
    __shared__ int ss[SCAN_BS];
    const int t = threadIdx.x;
    const int i = blockIdx.x * SCAN_BS + t;
    int v = (i < N_NODES) ? deg[i] : 0;
    ss[t] = v;
    __syncthreads();
    for (int off = 1; off < SCAN_BS; off <<= 1) {
        int a = (t >= off) ? ss[t - off] : 0;
        __syncthreads();
        ss[t] += a;
        __syncthreads();
    }
    if (i < N_NODES) scanout[i] = ss[t] - v;
    if (t == SCAN_BS - 1) bsum[blockIdx.x] = ss[t];
}

__global__ __launch_bounds__(128) void k_scan2(int* __restrict__ bsum) {
    __shared__ int ss[128];
    const int t = threadIdx.x;
    int v = (t < NSCAN) ? bsum[t] : 0;
    ss[t] = v;
    __syncthreads();
    for (int off = 1; off < 128; off <<= 1) {
        int a = (t >= off) ? ss[t - off] : 0;
        __syncthreads();
        ss[t] += a;
        __syncthreads();
    }
    if (t < NSCAN) bsum[t] = ss[t] - v;
}

__global__ __launch_bounds__(256) void k_scan3(
    const int* __restrict__ scanout, const int* __restrict__ bsum,
    int* __restrict__ rowstart, int* __restrict__ cursor) {
    int i = blockIdx.x * 256 + threadIdx.x;
    if (i < N_NODES) {
        int rs = scanout[i] + bsum[i / SCAN_BS];
        rowstart[i] = rs;
        cursor[i] = rs;
    }
    if (i == 0) rowstart[N_NODES] = N_EDGES;
}

// K_fill: CSR fill + permuted copies of src and basic (linear reads here,
// scattered fire-and-forget writes) so k_attn has only ONE gather stream.
__global__ __launch_bounds__(256) void k_fill(
    const int* __restrict__ dst, const int* __restrict__ src,
    const float* __restrict__ basic, int* __restrict__ cursor,
    int* __restrict__ eidx, int* __restrict__ srcperm,
    float* __restrict__ bperm) {
    int e = blockIdx.x * 256 + threadIdx.x;
    int pos = atomicAdd(&cursor[dst[e]], 1);
    eidx[pos] = e;
    srcperm[pos] = src[e];
    bperm[pos] = basic[e];
}

// K2: fused logits+softmax, single edge pass, 2-deep unroll.
// Linear reads of srcperm/bperm; only kv row is gathered.
__global__ __launch_bounds__(256) void k_attn(
    const ushort_t* __restrict__ kv, const ushort_t* __restrict__ qv,
    const float* __restrict__ bperm, const float* __restrict__ Wdis,
    const int* __restrict__ srcperm, const int* __restrict__ rowstart,
    float* __restrict__ aperm, float* __restrict__ sinv) {
    const int t = threadIdx.x;
    const int lane = t & 63, wv = t >> 6;
    const int n = blockIdx.x * 4 + wv;
    const int j = lane >> 3, h = lane & 7;
    const int rs = rowstart[n], re = rowstart[n + 1];
    const float wd = Wdis[h];
    const ushort_t* qp = qv + (size_t)n * D + h * DH;
    u16x8 q0 = *(const u16x8*)qp;
    u16x8 q1 = *(const u16x8*)(qp + 8);
    float qf[16];
#pragma unroll
    for (int i = 0; i < 8; ++i) { qf[i] = b2f(q0[i]); qf[8 + i] = b2f(q1[i]); }

    float sl = 0.f;
    int base = rs;
    for (; base + 16 <= re; base += 16) {
        int pA = base + j, pB = base + 8 + j;
        int sA = srcperm[pA], sB = srcperm[pB];
        float baA = bperm[pA], baB = bperm[pB];
        const ushort_t* kpA = kv + (size_t)sA * D + h * DH;
        const ushort_t* kpB = kv + (size_t)sB * D + h * DH;
        u16x8 kA0 = *(const u16x8*)kpA;
        u16x8 kA1 = *(const u16x8*)(kpA + 8);
        u16x8 kB0 = *(const u16x8*)kpB;
        u16x8 kB1 = *(const u16x8*)(kpB + 8);
        float accA = 0.f, accB = 0.f;
#pragma unroll
        for (int i = 0; i < 8; ++i) {
            accA += qf[i] * b2f(kA0[i]) + qf[8 + i] * b2f(kA1[i]);
            accB += qf[i] * b2f(kB0[i]) + qf[8 + i] * b2f(kB1[i]);
        }
        float pAp = expf(accA * 0.25f + baA * wd);
        float pBp = expf(accB * 0.25f + baB * wd);
        aperm[(size_t)pA * NH + h] = pAp;
        aperm[(size_t)pB * NH + h] = pBp;
        sl += pAp + pBp;
    }
    for (; base < re; base += 8) {
        int pos = base + j;
        if (pos < re) {
            int sc = srcperm[pos];
            const ushort_t* kp = kv + (size_t)sc * D + h * DH;
            u16x8 k0 = *(const u16x8*)kp;
            u16x8 k1 = *(const u16x8*)(kp + 8);
            float acc = 0.f;
#pragma unroll
            for (int i = 0; i < 8; ++i)
                acc += qf[i] * b2f(k0[i]) + qf[8 + i] * b2f(k1[i]);
            float p = expf(acc * 0.25f + bperm[pos] * wd);
            aperm[(size_t)pos * NH + h] = p;
            sl += p;
        }
    }
    sl += __shfl_xor(sl, 8);
    sl += __shfl_xor(sl, 16);
    sl += __shfl_xor(sl, 32);
    if (lane < 8) sinv[(size_t)n * NH + h] = (sl > 0.f) ? 1.f / sl : 0.f;
}

// K3: fused per-head weighted-sum + projection (4-deep unroll, r17-proven).
__global__ __launch_bounds__(256) void k_hsum(
    const float* __restrict__ bond, const float* __restrict__ Wv,
    const float* __restrict__ aperm, const float* __restrict__ sinv,
    const int* __restrict__ rowstart, const int* __restrict__ eidx,
    float* __restrict__ ft) {
    __shared__ short slds[8 * 16 * 128];  // [head][node][k] bf16, swizzled
    __shared__ float sivlds[GN * 8];
    __shared__ int srs[GN + 1];
    const int t = threadIdx.x;
    const int lane = t & 63, w = t >> 6;
    const int lr = lane & 15, lg = lane >> 4;
    const int n0 = blockIdx.x * GN;
    if (t < GN + 1) srs[t] = rowstart[n0 + t];
    if (t < GN * 8) sivlds[t] = sinv[(size_t)n0 * 8 + t];
    __syncthreads();

    const int c0 = lane * 2;
    const int chunk = lane >> 2;
    const int elo = (lane * 2) & 7;

#pragma unroll
    for (int i = 0; i < 4; ++i) {
        int ln = w + i * 4;
        int rs = srs[ln], re = srs[ln + 1];
        float sacc[8][2];
#pragma unroll
        for (int h = 0; h < 8; ++h) { sacc[h][0] = 0.f; sacc[h][1] = 0.f; }
        int pos = rs;
        for (; pos + 4 <= re; pos += 4) {
            int e0 = eidx[pos], e1 = eidx[pos + 1];
            int e2 = eidx[pos + 2], e3 = eidx[pos + 3];
            float2 b0 = *(const float2*)&bond[(size_t)e0 * D + c0];
            float2 b1 = *(const float2*)&bond[(size_t)e1 * D + c0];
            float2 b2 = *(const float2*)&bond[(size_t)e2 * D + c0];
            float2 b3 = *(const float2*)&bond[(size_t)e3 * D + c0];
            float4 a00 = *(const float4*)&aperm[(size_t)pos * 8];
            float4 a01 = *(const float4*)&aperm[(size_t)pos * 8 + 4];
            float4 a10 = *(const float4*)&aperm[(size_t)(pos + 1) * 8];
            float4 a11 = *(const float4*)&aperm[(size_t)(pos + 1) * 8 + 4];
            float4 a20 = *(const float4*)&aperm[(size_t)(pos + 2) * 8];
            float4 a21 = *(const float4*)&aperm[(size_t)(pos + 2) * 8 + 4];
            float4 a30 = *(const float4*)&aperm[(size_t)(pos + 3) * 8];
            float4 a31 = *(const float4*)&aperm[(size_t)(pos + 3) * 8 + 4];
            const float a0v[8] = {a00.x, a00.y, a00.z, a00.w,
                                  a01.x, a01.y, a01.z, a01.w};
            const float a1v[8] = {a10.x, a10.y, a10.z, a10.w,
                                  a11.x, a11.y, a11.z, a11.w};
            const float a2v[8] = {a20.x, a20.y, a20.z, a20.w,
                                  a21.x, a21.y, a21.z, a21.w};
            const float a3v[8] = {a30.x, a30.y, a30.z, a30.w,
                                  a31.x, a31.y, a31.z, a31.w};
#pragma unroll
            for (int h = 0; h < 8; ++h) {
                sacc[h][0] += a0v[h] * b0.x + a1v[h] * b1.x +
                              a2v[h] * b2.x + a3v[h] * b3.x;
                sacc[h][1] += a0v[h] * b0.y + a1v[h] * b1.y +
                              a2v[h] * b2.y + a3v[h] * b3.y;
            }
        }
        for (; pos < re; ++pos) {
            int e = eidx[pos];
            float2 b = *(const float2*)&bond[(size_t)e * D + c0];
            float4 a0 = *(const float4*)&aperm[(size_t)pos * 8];
            float4 a1 = *(const float4*)&aperm[(size_t)pos * 8 + 4];
            const float av[8] = {a0.x, a0.y, a0.z, a0.w,
                                 a1.x, a1.y, a1.z, a1.w};
#pragma unroll
            for (int h = 0; h < 8; ++h) {
                sacc[h][0] += av[h] * b.x;
                sacc[h][1] += av[h] * b.y;
            }
        }
#pragma unroll
        for (int h = 0; h < 8; ++h) {
            float siv = sivlds[ln * 8 + h];
            unsigned u = (unsigned)(unsigned short)f2b(sacc[h][0] * siv) |
                         ((unsigned)(unsigned short)f2b(sacc[h][1] * siv) << 16);
            *(unsigned*)&slds[(h * 16 + ln) * 128 +
                              ((chunk ^ (ln & 7)) << 3) + elo] = u;
        }
    }
    __syncthreads();

    // ---- Phase B: projection. Wave w owns heads 2w, 2w+1. ----
    bf16x8 bfr[2][4];
#pragma unroll
    for (int nn = 0; nn < 2; ++nn) {
        int col = (2 * w + nn) * 16 + lr;
#pragma unroll
        for (int ks = 0; ks < 4; ++ks) {
            const float4* gp = (const float4*)(Wv + (size_t)col * D + ks * 32 + lg * 8);
            float4 f0 = gp[0], f1 = gp[1];
            bf16x8 v;
            v[0] = f2b(f0.x); v[1] = f2b(f0.y); v[2] = f2b(f0.z); v[3] = f2b(f0.w);
            v[4] = f2b(f1.x); v[5] = f2b(f1.y); v[6] = f2b(f1.z); v[7] = f2b(f1.w);
            bfr[nn][ks] = v;
        }
    }
    f32x4 acc[2];
#pragma unroll
    for (int nn = 0; nn < 2; ++nn) acc[nn] = (f32x4){0.f, 0.f, 0.f, 0.f};
#pragma unroll
    for (int ks = 0; ks < 4; ++ks) {
        int ck = ks * 4 + lg;
#pragma unroll
        for (int nn = 0; nn < 2; ++nn) {
            int h = 2 * w + nn;
            bf16x8 sf = *(const bf16x8*)&slds[(h * 16 + lr) * 128 +
                                              ((ck ^ (lr & 7)) << 3)];
            acc[nn] = __builtin_amdgcn_mfma_f32_16x16x32_bf16(
                bfr[nn][ks], sf, acc[nn], 0, 0, 0);  // swapped operands
        }
    }
#pragma unroll
    for (int nn = 0; nn < 2; ++nn) {
        float4 o = {acc[nn][0], acc[nn][1], acc[nn][2], acc[nn][3]};
        *(float4*)&ft[(size_t)(n0 + lr) * D + (2 * w + nn) * 16 + lg * 4] = o;
    }
}

// K5: MFMA node kernel. 32 nodes/block, 4 waves.
__global__ __launch_bounds__(256, 2) void k_node(
    const float* __restrict__ ft, const float* __restrict__ x,
    const float* __restrict__ Wb, const float* __restrict__ W1,
    const float* __restrict__ W2, const float* __restrict__ g_ln,
    const float* __restrict__ b_ln, float* __restrict__ out) {
    __shared__ float hs[NPB][132];
    __shared__ short hA[NPB * 128];
    __shared__ short hid[NPB * 256];
    __shared__ float ylds[NPB][132];
    const int t = threadIdx.x;
    const int lane = t & 63, w = t >> 6;
    const int lr = lane & 15, lg = lane >> 4;
    const int n0 = blockIdx.x * NPB;
    const int c0 = lane * 2;

    const float2 wb0 = *(const float2*)&Wb[c0];
    const float2 wb1 = *(const float2*)&Wb[128 + c0];
    const float2 wb2 = *(const float2*)&Wb[256 + c0];
    const float2 gv = *(const float2*)&g_ln[c0];
    const float2 bv = *(const float2*)&b_ln[c0];
#pragma unroll
    for (int i = 0; i < 8; ++i) {
        int n = w * 8 + i;
        int gn = n0 + n;
        float2 fv = {0.f, 0.f}, xv = {0.f, 0.f};
        if (gn < N_NODES) {
            fv = *(const float2*)&ft[(size_t)gn * D + c0];
            xv = *(const float2*)&x[(size_t)gn * D + c0];
        }
        float part = fv.x * wb0.x + fv.y * wb0.y + xv.x * wb1.x + xv.y * wb1.y +
                     (fv.x - xv.x) * wb2.x + (fv.y - xv.y) * wb2.y;
        float beta = 1.f / (1.f + expf(-wred(part)));
        float hex = beta * xv.x + (1.f - beta) * fv.x;
        float hey = beta * xv.y + (1.f - beta) * fv.y;
        hs[n][c0] = hex;
        hs[n][c0 + 1] = hey;
        float mu = wred(hex + hey) * (1.f / 128.f);
        float dx = hex - mu, dy = hey - mu;
        float var = wred(dx * dx + dy * dy) * (1.f / 128.f);
        float rs = rsqrtf(var + LN_EPS);
        float h0 = dx * rs * gv.x + bv.x;
        float h1 = dy * rs * gv.y + bv.y;
        unsigned u = (unsigned)(unsigned short)f2b(h0) |
                     ((unsigned)(unsigned short)f2b(h1) << 16);
        int phys = (lane >> 2) ^ (n & 7);
        ((unsigned*)hA)[n * 64 + phys * 4 + (lane & 3)] = u;
    }
    __syncthreads();

    {
        bf16x8 b1[4][4];
#pragma unroll
        for (int nt = 0; nt < 4; ++nt) {
            int col = w * 64 + nt * 16 + lr;
#pragma unroll
            for (int ks = 0; ks < 4; ++ks) {
                const float4* gp = (const float4*)(W1 + (size_t)col * D + ks * 32 + lg * 8);
                float4 f0 = gp[0], f1 = gp[1];
                bf16x8 v;
                v[0] = f2b(f0.x); v[1] = f2b(f0.y); v[2] = f2b(f0.z); v[3] = f2b(f0.w);
                v[4] = f2b(f1.x); v[5] = f2b(f1.y); v[6] = f2b(f1.z); v[7] = f2b(f1.w);
                b1[nt][ks] = v;
            }
        }
        f32x4 acc1[2][4];
#pragma unroll
        for (int m = 0; m < 2; ++m)
#pragma unroll
            for (int nt = 0; nt < 4; ++nt) acc1[m][nt] = (f32x4){0.f, 0.f, 0.f, 0.f};
#pragma unroll
        for (int ks = 0; ks < 4; ++ks) {
            int chunk = ks * 4 + lg;
#pragma unroll
            for (int m = 0; m < 2; ++m) {
                int row = m * 16 + lr;
                bf16x8 af = *(const bf16x8*)&hA[row * 128 + ((chunk ^ (row & 7)) << 3)];
#pragma unroll
                for (int nt = 0; nt < 4; ++nt)
                    acc1[m][nt] = __builtin_amdgcn_mfma_f32_16x16x32_bf16(
                        af, b1[nt][ks], acc1[m][nt], 0, 0, 0);
            }
        }
#pragma unroll
        for (int m = 0; m < 2; ++m)
#pragma unroll
            for (int nt = 0; nt < 4; ++nt)
#pragma unroll
                for (int r = 0; r < 4; ++r) {
                    int node = m * 16 + lg * 4 + r;
                    int col = w * 64 + nt * 16 + lr;
                    float v = fmaxf(acc1[m][nt][r], 0.f);
                    hid[node * 256 + (((col >> 3) ^ (node & 7)) << 3) + (col & 7)] = f2b(v);
                }
    }
    __syncthreads();

    {
        bf16x8 b2[2][8];
#pragma unroll
        for (int nt = 0; nt < 2; ++nt) {
            int col = w * 32 + nt * 16 + lr;
#pragma unroll
            for (int ks = 0; ks < 8; ++ks) {
                const float4* gp = (const float4*)(W2 + (size_t)col * DFF + ks * 32 + lg * 8);
                float4 f0 = gp[0], f1 = gp[1];
                bf16x8 v;
                v[0] = f2b(f0.x); v[1] = f2b(f0.y); v[2] = f2b(f0.z); v[3] = f2b(f0.w);
                v[4] = f2b(f1.x); v[5] = f2b(f1.y); v[6] = f2b(f1.z); v[7] = f2b(f1.w);
                b2[nt][ks] = v;
            }
        }
        f32x4 acc2[2][2];
#pragma unroll
        for (int m = 0; m < 2; ++m)
#pragma unroll
            for (int nt = 0; nt < 2; ++nt) acc2[m][nt] = (f32x4){0.f, 0.f, 0.f, 0.f};
#pragma unroll
        for (int ks = 0; ks < 8; ++ks) {
            int chunk = ks * 4 + lg;
#pragma unroll
            for (int m = 0; m < 2; ++m) {
                int row = m * 16 + lr;
                bf16x8 af = *(const bf16x8*)&hid[row * 256 + ((chunk ^ (row & 7)) << 3)];
#pragma unroll
                for (int nt = 0; nt < 2; ++nt)
                    acc2[m][nt] = __builtin_amdgcn_mfma_f32_16x16x32_bf16(
                        af, b2[nt][ks], acc2[m][nt], 0, 0, 0);
            }
        }
#pragma unroll
        for (int m = 0; m < 2; ++m)
#pragma unroll
            for (int nt = 0; nt < 2; ++nt)
#pragma unroll
                for (int r = 0; r < 4; ++r) {
                    int node = m * 16 + lg * 4 + r;
                    int col = w * 32 + nt * 16 + lr;
                    ylds[node][col] = acc2[m][nt][r] + hs[node][col];
                }
    }
    __syncthreads();

#pragma unroll
    for (int i = 0; i < 8; ++i) {
        int n = w * 8 + i;
        int gn = n0 + n;
        float y0 = ylds[n][c0], y1 = ylds[n][c0 + 1];
        float mu = wred(y0 + y1) * (1.f / 128.f);
        float d0 = y0 - mu, d1 = y1 - mu;
        float var = wred(d0 * d0 + d1 * d1) * (1.f / 128.f);
        float rs = rsqrtf(var + LN_EPS);
        if (gn < N_NODES) {
            float2 o = {d0 * rs, d1 * rs};
            *(float2*)&out[(size_t)gn * D + c0] = o;
        }
    }
}

extern "C" void kernel_launch(void* const* d_in, const int* in_sizes, int n_in,
                              void* d_out, int out_size, void* d_ws, size_t ws_size,
                              hipStream_t stream) {
    const float* bond = (const float*)d_in[0];
    const float* x    = (const float*)d_in[1];
    const float* basic= (const float*)d_in[2];
    const float* Wk   = (const float*)d_in[3];
    const float* Wq   = (const float*)d_in[4];
    const float* Wv   = (const float*)d_in[5];
    const float* Wdis = (const float*)d_in[6];
    const float* Wb   = (const float*)d_in[7];
    const float* W1   = (const float*)d_in[8];
    const float* W2   = (const float*)d_in[9];
    const float* g_ln = (const float*)d_in[10];
    const float* b_ln = (const float*)d_in[11];
    const int* src    = (const int*)d_in[12];
    const int* dst    = (const int*)d_in[13];
    float* out = (float*)d_out;

    // ws layout (~89 MB):
    ushort_t* kbf = (ushort_t*)d_ws;                    // N*128 bf16
    ushort_t* qbf = kbf + (size_t)N_NODES * D;          // N*128 bf16
    float* aperm = (float*)(qbf + (size_t)N_NODES * D); // E*8 f32 (unnorm p)
    float* ftb   = aperm + (size_t)N_EDGES * NH;        // N*128 f32
    float* sinvb = ftb + (size_t)N_NODES * D;           // N*8 f32
    int* deg     = (int*)(sinvb + (size_t)N_NODES * NH);// N [zeroed by k_zero]
    int* scanout = deg + N_NODES;                       // N
    int* bsum    = scanout + N_NODES;                   // 128
    int* rowstart= bsum + 128;                          // N+1
    int* cursor  = rowstart + N_NODES + 1;              // N
    int* eidx    = cursor + N_NODES;                    // E
    int* srcperm = eidx + N_EDGES;                      // E
    float* bperm = (float*)(srcperm + N_EDGES);         // E

    k_zero<<<(N_NODES + 255) / 256, 256, 0, stream>>>(deg);
    k_qkproj<<<N_NODES / 16, 128, 0, stream>>>(x, Wk, Wq, kbf, qbf);
    k_hist<<<N_EDGES / 256, 256, 0, stream>>>(dst, deg);
    k_scan1<<<NSCAN, SCAN_BS, 0, stream>>>(deg, scanout, bsum);
    k_scan2<<<1, 128, 0, stream>>>(bsum);
    k_scan3<<<(N_NODES + 255) / 256, 256, 0, stream>>>(scanout, bsum, rowstart, cursor);
    k_fill<<<N_EDGES / 256, 256, 0, stream>>>(dst, src, basic, cursor,
                                              eidx, srcperm, bperm);
    k_attn<<<N_NODES / 4, 256, 0, stream>>>(kbf, qbf, bperm, Wdis, srcperm,
                                            rowstart, aperm, sinvb);
    k_hsum<<<N_NODES / GN, 256, 0, stream>>>(bond, Wv, aperm, sinvb,
                                             rowstart, eidx, ftb);
    k_node<<<(N_NODES + NPB - 1) / NPB, 256, 0, stream>>>(ftb, x, Wb, W1, W2,
                                                          g_ln, b_ln, out);
}

// Round 19
// 446.236 us; speedup vs baseline: 1.2479x; 1.0952x over previous
//
#include <hip/hip_runtime.h>
#include <hip/hip_bf16.h>

#define N_NODES 50000
#define N_EDGES 800000
#define D 128
#define NH 8
#define DH 16
#define DFF 256
#define LN_EPS 1e-5f
#define GN 16
#define NPB 32
#define SCAN_BS 512
#define NSCAN ((N_NODES + SCAN_BS - 1) / SCAN_BS)  // 98

typedef __attribute__((ext_vector_type(8))) short bf16x8;
typedef __attribute__((ext_vector_type(8))) unsigned short u16x8;
typedef __attribute__((ext_vector_type(4))) unsigned short u16x4;
typedef __attribute__((ext_vector_type(4))) float f32x4;
typedef unsigned short ushort_t;

__device__ __forceinline__ float wred(float v) {
#pragma unroll
    for (int o = 32; o; o >>= 1) v += __shfl_xor(v, o);
    return v;
}

// fp32 -> bf16 (RNE) bit helper
__device__ __forceinline__ short f2b(float f) {
    unsigned u = __float_as_uint(f);
    unsigned r = u + 0x7fffu + ((u >> 16) & 1u);
    return (short)(r >> 16);
}
__device__ __forceinline__ float b2f(unsigned short u) {
    return __uint_as_float((unsigned)u << 16);
}

// K0: zero the degree array.
__global__ __launch_bounds__(256) void k_zero(int* __restrict__ p) {
    int i = blockIdx.x * 256 + threadIdx.x;
    if (i < N_NODES) p[i] = 0;
}

// K1: q/k projections via MFMA. 32 nodes/block, 4 waves; wave w owns
// cols w*64..+63 of the virtual [Wk;Wq] (256 cols). Swapped-operand MFMA:
// lane holds 4 consecutive out-cols of one node -> packed 8-B bf16 stores.
__global__ __launch_bounds__(256) void k_qkproj(
    const float* __restrict__ x, const float* __restrict__ Wk,
    const float* __restrict__ Wq, ushort_t* __restrict__ kout,
    ushort_t* __restrict__ qout) {
    __shared__ short xlds[32 * 128];  // x rows bf16, chunk-XOR swizzled
    const int t = threadIdx.x;
    const int lane = t & 63, w = t >> 6;
    const int lr = lane & 15, lg = lane >> 4;
    const int n0 = blockIdx.x * 32;

#pragma unroll
    for (int i = 0; i < 2; ++i) {
        int cid = i * 256 + t;
        int row = cid >> 4, cx = cid & 15;
        bf16x8 v = {0, 0, 0, 0, 0, 0, 0, 0};
        if (n0 + row < N_NODES) {
            const float4* gp = (const float4*)(x + (size_t)(n0 + row) * D + cx * 8);
            float4 f0 = gp[0], f1 = gp[1];
            v[0] = f2b(f0.x); v[1] = f2b(f0.y); v[2] = f2b(f0.z); v[3] = f2b(f0.w);
            v[4] = f2b(f1.x); v[5] = f2b(f1.y); v[6] = f2b(f1.z); v[7] = f2b(f1.w);
        }
        *(bf16x8*)&xlds[row * 128 + ((cx ^ (row & 7)) << 3)] = v;
    }
    __syncthreads();

    // weight fragments (wave-owned 4 col-tiles x 4 k-chunks)
    bf16x8 bfr[4][4];
#pragma unroll
    for (int nt = 0; nt < 4; ++nt) {
        int col = w * 64 + nt * 16 + lr;
        const float* Wrow = (col < 128) ? (Wk + (size_t)col * D)
                                        : (Wq + (size_t)(col - 128) * D);
#pragma unroll
        for (int ks = 0; ks < 4; ++ks) {
            const float4* gp = (const float4*)(Wrow + ks * 32 + lg * 8);
            float4 f0 = gp[0], f1 = gp[1];
            bf16x8 v;
            v[0] = f2b(f0.x); v[1] = f2b(f0.y); v[2] = f2b(f0.z); v[3] = f2b(f0.w);
            v[4] = f2b(f1.x); v[5] = f2b(f1.y); v[6] = f2b(f1.z); v[7] = f2b(f1.w);
            bfr[nt][ks] = v;
        }
    }

    f32x4 acc[2][4];
#pragma unroll
    for (int m = 0; m < 2; ++m)
#pragma unroll
        for (int nt = 0; nt < 4; ++nt) acc[m][nt] = (f32x4){0.f, 0.f, 0.f, 0.f};
#pragma unroll
    for (int ks = 0; ks < 4; ++ks) {
        int ck = ks * 4 + lg;
#pragma unroll
        for (int m = 0; m < 2; ++m) {
            int row = m * 16 + lr;
            bf16x8 af = *(const bf16x8*)&xlds[row * 128 + ((ck ^ (row & 7)) << 3)];
#pragma unroll
            for (int nt = 0; nt < 4; ++nt)
                acc[m][nt] = __builtin_amdgcn_mfma_f32_16x16x32_bf16(
                    bfr[nt][ks], af, acc[m][nt], 0, 0, 0);  // swapped operands
        }
    }
    // lane holds out[node = n0+m*16+lr][col = w*64 + nt*16 + lg*4 + r]
#pragma unroll
    for (int m = 0; m < 2; ++m) {
        int node = n0 + m * 16 + lr;
        if (node < N_NODES) {
#pragma unroll
            for (int nt = 0; nt < 4; ++nt) {
                int col = w * 64 + nt * 16 + lg * 4;
                u16x4 o;
#pragma unroll
                for (int r = 0; r < 4; ++r) o[r] = (ushort_t)f2b(acc[m][nt][r]);
                if (col < 128)
                    *(u16x4*)&kout[(size_t)node * D + col] = o;
                else
                    *(u16x4*)&qout[(size_t)node * D + col - 128] = o;
            }
        }
    }
}

// CSR build ---------------------------------------------------------------
__global__ __launch_bounds__(256) void k_hist(const int* __restrict__ dst,
                                              int* __restrict__ deg) {
    int e = blockIdx.x * 256 + threadIdx.x;
    atomicAdd(&deg[dst[e]], 1);
}

__global__ __launch_bounds__(SCAN_BS) void k_scan1(
    const int* __restrict__ deg, int* __restrict__ scanout,
    int* __restrict__ bsum) {
    __shared__ int ss[SCAN_BS];
    const int t = threadIdx.x;
    const int i = blockIdx.x * SCAN_BS + t;
    int v = (i < N_NODES) ? deg[i] : 0;
    ss[t] = v;
    __syncthreads();
    for (int off = 1; off < SCAN_BS; off <<= 1) {
        int a = (t >= off) ? ss[t - off] : 0;
        __syncthreads();
        ss[t] += a;
        __syncthreads();
    }
    if (i < N_NODES) scanout[i] = ss[t] - v;
    if (t == SCAN_BS - 1) bsum[blockIdx.x] = ss[t];
}

__global__ __launch_bounds__(128) void k_scan2(int* __restrict__ bsum) {
    __shared__ int ss[128];
    const int t = threadIdx.x;
    int v = (t < NSCAN) ? bsum[t] : 0;
    ss[t] = v;
    __syncthreads();
    for (int off = 1; off < 128; off <<= 1) {
        int a = (t >= off) ? ss[t - off] : 0;
        __syncthreads();
        ss[t] += a;
        __syncthreads();
    }
    if (t < NSCAN) bsum[t] = ss[t] - v;
}

__global__ __launch_bounds__(256) void k_scan3(
    const int* __restrict__ scanout, const int* __restrict__ bsum,
    int* __restrict__ rowstart, int* __restrict__ cursor) {
    int i = blockIdx.x * 256 + threadIdx.x;
    if (i < N_NODES) {
        int rs = scanout[i] + bsum[i / SCAN_BS];
        rowstart[i] = rs;
        cursor[i] = rs;
    }
    if (i == 0) rowstart[N_NODES] = N_EDGES;
}

// K_fill: CSR fill + permuted copies of src and basic.
__global__ __launch_bounds__(256) void k_fill(
    const int* __restrict__ dst, const int* __restrict__ src,
    const float* __restrict__ basic, int* __restrict__ cursor,
    int* __restrict__ eidx, int* __restrict__ srcperm,
    float* __restrict__ bperm) {
    int e = blockIdx.x * 256 + threadIdx.x;
    int pos = atomicAdd(&cursor[dst[e]], 1);
    eidx[pos] = e;
    srcperm[pos] = src[e];
    bperm[pos] = basic[e];
}

// K2: fused logits+softmax, single edge pass, 2-deep unroll.
__global__ __launch_bounds__(256) void k_attn(
    const ushort_t* __restrict__ kv, const ushort_t* __restrict__ qv,
    const float* __restrict__ bperm, const float* __restrict__ Wdis,
    const int* __restrict__ srcperm, const int* __restrict__ rowstart,
    float* __restrict__ aperm, float* __restrict__ sinv) {
    const int t = threadIdx.x;
    const int lane = t & 63, wv = t >> 6;
    const int n = blockIdx.x * 4 + wv;
    const int j = lane >> 3, h = lane & 7;
    const int rs = rowstart[n], re = rowstart[n + 1];
    const float wd = Wdis[h];
    const ushort_t* qp = qv + (size_t)n * D + h * DH;
    u16x8 q0 = *(const u16x8*)qp;
    u16x8 q1 = *(const u16x8*)(qp + 8);
    float qf[16];
#pragma unroll
    for (int i = 0; i < 8; ++i) { qf[i] = b2f(q0[i]); qf[8 + i] = b2f(q1[i]); }

    float sl = 0.f;
    int base = rs;
    for (; base + 16 <= re; base += 16) {
        int pA = base + j, pB = base + 8 + j;
        int sA = srcperm[pA], sB = srcperm[pB];
        float baA = bperm[pA], baB = bperm[pB];
        const ushort_t* kpA = kv + (size_t)sA * D + h * DH;
        const ushort_t* kpB = kv + (size_t)sB * D + h * DH;
        u16x8 kA0 = *(const u16x8*)kpA;
        u16x8 kA1 = *(const u16x8*)(kpA + 8);
        u16x8 kB0 = *(const u16x8*)kpB;
        u16x8 kB1 = *(const u16x8*)(kpB + 8);
        float accA = 0.f, accB = 0.f;
#pragma unroll
        for (int i = 0; i < 8; ++i) {
            accA += qf[i] * b2f(kA0[i]) + qf[8 + i] * b2f(kA1[i]);
            accB += qf[i] * b2f(kB0[i]) + qf[8 + i] * b2f(kB1[i]);
        }
        float pAp = expf(accA * 0.25f + baA * wd);
        float pBp = expf(accB * 0.25f + baB * wd);
        aperm[(size_t)pA * NH + h] = pAp;
        aperm[(size_t)pB * NH + h] = pBp;
        sl += pAp + pBp;
    }
    for (; base < re; base += 8) {
        int pos = base + j;
        if (pos < re) {
            int sc = srcperm[pos];
            const ushort_t* kp = kv + (size_t)sc * D + h * DH;
            u16x8 k0 = *(const u16x8*)kp;
            u16x8 k1 = *(const u16x8*)(kp + 8);
            float acc = 0.f;
#pragma unroll
            for (int i = 0; i < 8; ++i)
                acc += qf[i] * b2f(k0[i]) + qf[8 + i] * b2f(k1[i]);
            float p = expf(acc * 0.25f + bperm[pos] * wd);
            aperm[(size_t)pos * NH + h] = p;
            sl += p;
        }
    }
    sl += __shfl_xor(sl, 8);
    sl += __shfl_xor(sl, 16);
    sl += __shfl_xor(sl, 32);
    if (lane < 8) sinv[(size_t)n * NH + h] = (sl > 0.f) ? 1.f / sl : 0.f;
}

// K3: fused per-head weighted-sum + projection (4-deep unroll, r17-proven).
__global__ __launch_bounds__(256) void k_hsum(
    const float* __restrict__ bond, const float* __restrict__ Wv,
    const float* __restrict__ aperm, const float* __restrict__ sinv,
    const int* __restrict__ rowstart, const int* __restrict__ eidx,
    float* __restrict__ ft) {
    __shared__ short slds[8 * 16 * 128];  // [head][node][k] bf16, swizzled
    __shared__ float sivlds[GN * 8];
    __shared__ int srs[GN + 1];
    const int t = threadIdx.x;
    const int lane = t & 63, w = t >> 6;
    const int lr = lane & 15, lg = lane >> 4;
    const int n0 = blockIdx.x * GN;
    if (t < GN + 1) srs[t] = rowstart[n0 + t];
    if (t < GN * 8) sivlds[t] = sinv[(size_t)n0 * 8 + t];
    __syncthreads();

    const int c0 = lane * 2;
    const int chunk = lane >> 2;
    const int elo = (lane * 2) & 7;

#pragma unroll
    for (int i = 0; i < 4; ++i) {
        int ln = w + i * 4;
        int rs = srs[ln], re = srs[ln + 1];
        float sacc[8][2];
#pragma unroll
        for (int h = 0; h < 8; ++h) { sacc[h][0] = 0.f; sacc[h][1] = 0.f; }
        int pos = rs;
        for (; pos + 4 <= re; pos += 4) {
            int e0 = eidx[pos], e1 = eidx[pos + 1];
            int e2 = eidx[pos + 2], e3 = eidx[pos + 3];
            float2 b0 = *(const float2*)&bond[(size_t)e0 * D + c0];
            float2 b1 = *(const float2*)&bond[(size_t)e1 * D + c0];
            float2 b2 = *(const float2*)&bond[(size_t)e2 * D + c0];
            float2 b3 = *(const float2*)&bond[(size_t)e3 * D + c0];
            float4 a00 = *(const float4*)&aperm[(size_t)pos * 8];
            float4 a01 = *(const float4*)&aperm[(size_t)pos * 8 + 4];
            float4 a10 = *(const float4*)&aperm[(size_t)(pos + 1) * 8];
            float4 a11 = *(const float4*)&aperm[(size_t)(pos + 1) * 8 + 4];
            float4 a20 = *(const float4*)&aperm[(size_t)(pos + 2) * 8];
            float4 a21 = *(const float4*)&aperm[(size_t)(pos + 2) * 8 + 4];
            float4 a30 = *(const float4*)&aperm[(size_t)(pos + 3) * 8];
            float4 a31 = *(const float4*)&aperm[(size_t)(pos + 3) * 8 + 4];
            const float a0v[8] = {a00.x, a00.y, a00.z, a00.w,
                                  a01.x, a01.y, a01.z, a01.w};
            const float a1v[8] = {a10.x, a10.y, a10.z, a10.w,
                                  a11.x, a11.y, a11.z, a11.w};
            const float a2v[8] = {a20.x, a20.y, a20.z, a20.w,
                                  a21.x, a21.y, a21.z, a21.w};
            const float a3v[8] = {a30.x, a30.y, a30.z, a30.w,
                                  a31.x, a31.y, a31.z, a31.w};
#pragma unroll
            for (int h = 0; h < 8; ++h) {
                sacc[h][0] += a0v[h] * b0.x + a1v[h] * b1.x +
                              a2v[h] * b2.x + a3v[h] * b3.x;
                sacc[h][1] += a0v[h] * b0.y + a1v[h] * b1.y +
                              a2v[h] * b2.y + a3v[h] * b3.y;
            }
        }
        for (; pos < re; ++pos) {
            int e = eidx[pos];
            float2 b = *(const float2*)&bond[(size_t)e * D + c0];
            float4 a0 = *(const float4*)&aperm[(size_t)pos * 8];
            float4 a1 = *(const float4*)&aperm[(size_t)pos * 8 + 4];
            const float av[8] = {a0.x, a0.y, a0.z, a0.w,
                                 a1.x, a1.y, a1.z, a1.w};
#pragma unroll
            for (int h = 0; h < 8; ++h) {
                sacc[h][0] += av[h] * b.x;
                sacc[h][1] += av[h] * b.y;
            }
        }
#pragma unroll
        for (int h = 0; h < 8; ++h) {
            float siv = sivlds[ln * 8 + h];
            unsigned u = (unsigned)(unsigned short)f2b(sacc[h][0] * siv) |
                         ((unsigned)(unsigned short)f2b(sacc[h][1] * siv) << 16);
            *(unsigned*)&slds[(h * 16 + ln) * 128 +
                              ((chunk ^ (ln & 7)) << 3) + elo] = u;
        }
    }
    __syncthreads();

    // ---- Phase B: projection. Wave w owns heads 2w, 2w+1. ----
    bf16x8 bfr[2][4];
#pragma unroll
    for (int nn = 0; nn < 2; ++nn) {
        int col = (2 * w + nn) * 16 + lr;
#pragma unroll
        for (int ks = 0; ks < 4; ++ks) {
            const float4* gp = (const float4*)(Wv + (size_t)col * D + ks * 32 + lg * 8);
            float4 f0 = gp[0], f1 = gp[1];
            bf16x8 v;
            v[0] = f2b(f0.x); v[1] = f2b(f0.y); v[2] = f2b(f0.z); v[3] = f2b(f0.w);
            v[4] = f2b(f1.x); v[5] = f2b(f1.y); v[6] = f2b(f1.z); v[7] = f2b(f1.w);
            bfr[nn][ks] = v;
        }
    }
    f32x4 acc[2];
#pragma unroll
    for (int nn = 0; nn < 2; ++nn) acc[nn] = (f32x4){0.f, 0.f, 0.f, 0.f};
#pragma unroll
    for (int ks = 0; ks < 4; ++ks) {
        int ck = ks * 4 + lg;
#pragma unroll
        for (int nn = 0; nn < 2; ++nn) {
            int h = 2 * w + nn;
            bf16x8 sf = *(const bf16x8*)&slds[(h * 16 + lr) * 128 +
                                              ((ck ^ (lr & 7)) << 3)];
            acc[nn] = __builtin_amdgcn_mfma_f32_16x16x32_bf16(
                bfr[nn][ks], sf, acc[nn], 0, 0, 0);  // swapped operands
        }
    }
#pragma unroll
    for (int nn = 0; nn < 2; ++nn) {
        float4 o = {acc[nn][0], acc[nn][1], acc[nn][2], acc[nn][3]};
        *(float4*)&ft[(size_t)(n0 + lr) * D + (2 * w + nn) * 16 + lg * 4] = o;
    }
}

// K5: MFMA node kernel. 32 nodes/block, 4 waves.
__global__ __launch_bounds__(256, 2) void k_node(
    const float* __restrict__ ft, const float* __restrict__ x,
    const float* __restrict__ Wb, const float* __restrict__ W1,
    const float* __restrict__ W2, const float* __restrict__ g_ln,
    const float* __restrict__ b_ln, float* __restrict__ out) {
    __shared__ float hs[NPB][132];
    __shared__ short hA[NPB * 128];
    __shared__ short hid[NPB * 256];
    __shared__ float ylds[NPB][132];
    const int t = threadIdx.x;
    const int lane = t & 63, w = t >> 6;
    const int lr = lane & 15, lg = lane >> 4;
    const int n0 = blockIdx.x * NPB;
    const int c0 = lane * 2;

    const float2 wb0 = *(const float2*)&Wb[c0];
    const float2 wb1 = *(const float2*)&Wb[128 + c0];
    const float2 wb2 = *(const float2*)&Wb[256 + c0];
    const float2 gv = *(const float2*)&g_ln[c0];
    const float2 bv = *(const float2*)&b_ln[c0];
#pragma unroll
    for (int i = 0; i < 8; ++i) {
        int n = w * 8 + i;
        int gn = n0 + n;
        float2 fv = {0.f, 0.f}, xv = {0.f, 0.f};
        if (gn < N_NODES) {
            fv = *(const float2*)&ft[(size_t)gn * D + c0];
            xv = *(const float2*)&x[(size_t)gn * D + c0];
        }
        float part = fv.x * wb0.x + fv.y * wb0.y + xv.x * wb1.x + xv.y * wb1.y +
                     (fv.x - xv.x) * wb2.x + (fv.y - xv.y) * wb2.y;
        float beta = 1.f / (1.f + expf(-wred(part)));
        float hex = beta * xv.x + (1.f - beta) * fv.x;
        float hey = beta * xv.y + (1.f - beta) * fv.y;
        hs[n][c0] = hex;
        hs[n][c0 + 1] = hey;
        float mu = wred(hex + hey) * (1.f / 128.f);
        float dx = hex - mu, dy = hey - mu;
        float var = wred(dx * dx + dy * dy) * (1.f / 128.f);
        float rs = rsqrtf(var + LN_EPS);
        float h0 = dx * rs * gv.x + bv.x;
        float h1 = dy * rs * gv.y + bv.y;
        unsigned u = (unsigned)(unsigned short)f2b(h0) |
                     ((unsigned)(unsigned short)f2b(h1) << 16);
        int phys = (lane >> 2) ^ (n & 7);
        ((unsigned*)hA)[n * 64 + phys * 4 + (lane & 3)] = u;
    }
    __syncthreads();

    {
        bf16x8 b1[4][4];
#pragma unroll
        for (int nt = 0; nt < 4; ++nt) {
            int col = w * 64 + nt * 16 + lr;
#pragma unroll
            for (int ks = 0; ks < 4; ++ks) {
                const float4* gp = (const float4*)(W1 + (size_t)col * D + ks * 32 + lg * 8);
                float4 f0 = gp[0], f1 = gp[1];
                bf16x8 v;
                v[0] = f2b(f0.x); v[1] = f2b(f0.y); v[2] = f2b(f0.z); v[3] = f2b(f0.w);
                v[4] = f2b(f1.x); v[5] = f2b(f1.y); v[6] = f2b(f1.z); v[7] = f2b(f1.w);
                b1[nt][ks] = v;
            }
        }
        f32x4 acc1[2][4];
#pragma unroll
        for (int m = 0; m < 2; ++m)
#pragma unroll
            for (int nt = 0; nt < 4; ++nt) acc1[m][nt] = (f32x4){0.f, 0.f, 0.f, 0.f};
#pragma unroll
        for (int ks = 0; ks < 4; ++ks) {
            int chunk = ks * 4 + lg;
#pragma unroll
            for (int m = 0; m < 2; ++m) {
                int row = m * 16 + lr;
                bf16x8 af = *(const bf16x8*)&hA[row * 128 + ((chunk ^ (row & 7)) << 3)];
#pragma unroll
                for (int nt = 0; nt < 4; ++nt)
                    acc1[m][nt] = __builtin_amdgcn_mfma_f32_16x16x32_bf16(
                        af, b1[nt][ks], acc1[m][nt], 0, 0, 0);
            }
        }
#pragma unroll
        for (int m = 0; m < 2; ++m)
#pragma unroll
            for (int nt = 0; nt < 4; ++nt)
#pragma unroll
                for (int r = 0; r < 4; ++r) {
                    int node = m * 16 + lg * 4 + r;
                    int col = w * 64 + nt * 16 + lr;
                    float v = fmaxf(acc1[m][nt][r], 0.f);
                    hid[node * 256 + (((col >> 3) ^ (node & 7)) << 3) + (col & 7)] = f2b(v);
                }
    }
    __syncthreads();

    {
        bf16x8 b2[2][8];
#pragma unroll
        for (int nt = 0; nt < 2; ++nt) {
            int col = w * 32 + nt * 16 + lr;
#pragma unroll
            for (int ks = 0; ks < 8; ++ks) {
                const float4* gp = (const float4*)(W2 + (size_t)col * DFF + ks * 32 + lg * 8);
                float4 f0 = gp[0], f1 = gp[1];
                bf16x8 v;
                v[0] = f2b(f0.x); v[1] = f2b(f0.y); v[2] = f2b(f0.z); v[3] = f2b(f0.w);
                v[4] = f2b(f1.x); v[5] = f2b(f1.y); v[6] = f2b(f1.z); v[7] = f2b(f1.w);
                b2[nt][ks] = v;
            }
        }
        f32x4 acc2[2][2];
#pragma unroll
        for (int m = 0; m < 2; ++m)
#pragma unroll
            for (int nt = 0; nt < 2; ++nt) acc2[m][nt] = (f32x4){0.f, 0.f, 0.f, 0.f};
#pragma unroll
        for (int ks = 0; ks < 8; ++ks) {
            int chunk = ks * 4 + lg;
#pragma unroll
            for (int m = 0; m < 2; ++m) {
                int row = m * 16 + lr;
                bf16x8 af = *(const bf16x8*)&hid[row * 256 + ((chunk ^ (row & 7)) << 3)];
#pragma unroll
                for (int nt = 0; nt < 2; ++nt)
                    acc2[m][nt] = __builtin_amdgcn_mfma_f32_16x16x32_bf16(
                        af, b2[nt][ks], acc2[m][nt], 0, 0, 0);
            }
        }
#pragma unroll
        for (int m = 0; m < 2; ++m)
#pragma unroll
            for (int nt = 0; nt < 2; ++nt)
#pragma unroll
                for (int r = 0; r < 4; ++r) {
                    int node = m * 16 + lg * 4 + r;
                    int col = w * 32 + nt * 16 + lr;
                    ylds[node][col] = acc2[m][nt][r] + hs[node][col];
                }
    }
    __syncthreads();

#pragma unroll
    for (int i = 0; i < 8; ++i) {
        int n = w * 8 + i;
        int gn = n0 + n;
        float y0 = ylds[n][c0], y1 = ylds[n][c0 + 1];
        float mu = wred(y0 + y1) * (1.f / 128.f);
        float d0 = y0 - mu, d1 = y1 - mu;
        float var = wred(d0 * d0 + d1 * d1) * (1.f / 128.f);
        float rs = rsqrtf(var + LN_EPS);
        if (gn < N_NODES) {
            float2 o = {d0 * rs, d1 * rs};
            *(float2*)&out[(size_t)gn * D + c0] = o;
        }
    }
}

extern "C" void kernel_launch(void* const* d_in, const int* in_sizes, int n_in,
                              void* d_out, int out_size, void* d_ws, size_t ws_size,
                              hipStream_t stream) {
    const float* bond = (const float*)d_in[0];
    const float* x    = (const float*)d_in[1];
    const float* basic= (const float*)d_in[2];
    const float* Wk   = (const float*)d_in[3];
    const float* Wq   = (const float*)d_in[4];
    const float* Wv   = (const float*)d_in[5];
    const float* Wdis = (const float*)d_in[6];
    const float* Wb   = (const float*)d_in[7];
    const float* W1   = (const float*)d_in[8];
    const float* W2   = (const float*)d_in[9];
    const float* g_ln = (const float*)d_in[10];
    const float* b_ln = (const float*)d_in[11];
    const int* src    = (const int*)d_in[12];
    const int* dst    = (const int*)d_in[13];
    float* out = (float*)d_out;

    // ws layout (~89 MB):
    ushort_t* kbf = (ushort_t*)d_ws;                    // N*128 bf16
    ushort_t* qbf = kbf + (size_t)N_NODES * D;          // N*128 bf16
    float* aperm = (float*)(qbf + (size_t)N_NODES * D); // E*8 f32 (unnorm p)
    float* ftb   = aperm + (size_t)N_EDGES * NH;        // N*128 f32
    float* sinvb = ftb + (size_t)N_NODES * D;           // N*8 f32
    int* deg     = (int*)(sinvb + (size_t)N_NODES * NH);// N [zeroed by k_zero]
    int* scanout = deg + N_NODES;                       // N
    int* bsum    = scanout + N_NODES;                   // 128
    int* rowstart= bsum + 128;                          // N+1
    int* cursor  = rowstart + N_NODES + 1;              // N
    int* eidx    = cursor + N_NODES;                    // E
    int* srcperm = eidx + N_EDGES;                      // E
    float* bperm = (float*)(srcperm + N_EDGES);         // E

    k_zero<<<(N_NODES + 255) / 256, 256, 0, stream>>>(deg);
    k_qkproj<<<(N_NODES + 31) / 32, 256, 0, stream>>>(x, Wk, Wq, kbf, qbf);
    k_hist<<<N_EDGES / 256, 256, 0, stream>>>(dst, deg);
    k_scan1<<<NSCAN, SCAN_BS, 0, stream>>>(deg, scanout, bsum);
    k_scan2<<<1, 128, 0, stream>>>(bsum);
    k_scan3<<<(N_NODES + 255) / 256, 256, 0, stream>>>(scanout, bsum, rowstart, cursor);
    k_fill<<<N_EDGES / 256, 256, 0, stream>>>(dst, src, basic, cursor,
                                              eidx, srcperm, bperm);
    k_attn<<<N_NODES / 4, 256, 0, stream>>>(kbf, qbf, bperm, Wdis, srcperm,
                                            rowstart, aperm, sinvb);
    k_hsum<<<N_NODES / GN, 256, 0, stream>>>(bond, Wv, aperm, sinvb,
                                             rowstart, eidx, ftb);
    k_node<<<(N_NODES + NPB - 1) / NPB, 256, 0, stream>>>(ftb, x, Wb, W1, W2,
                                                          g_ln, b_ln, out);
}